// Round 10
// baseline (492.945 us; speedup 1.0000x reference)
//
#include <hip/hip_runtime.h>
#include <math.h>

#define NN 100000
#define EE 1600000
#define GG 64
#define NCLS 10

#define BSH 8                 // bucket = dst >> 8 (256 nodes per bucket)
#define NB 391                // ceil(NN / 256)
#define BCAP 4608             // fixed bucket capacity (mean 4092, sigma 64 -> 8 sigma)
#define EPS 2048              // edges per block in bscatter role (782 blocks)
#define SBLK 782              // ceil(EE / EPS)
#define CAPS 5120             // bsort LDS staging capacity (ints)
#define GB 1563               // ceil(NN / 64) gemm1 blocks

typedef unsigned int uint32;

__device__ __forceinline__ unsigned short f2bf(float f) {
    unsigned u = __float_as_uint(f);
    unsigned r = (u + 0x7fffu + ((u >> 16) & 1u)) >> 16;   // RNE
    return (unsigned short)r;
}

__device__ __forceinline__ float bf2f(unsigned short h) {
    return __uint_as_float((unsigned)h << 16);
}

// ---------------- bscatter (blockIdx%3==0) || gemm1 K=128 (else), R8-proven ----------------

__global__ __launch_bounds__(512) void pre_kernel(
    const int* __restrict__ src, const int* __restrict__ dst,
    int* __restrict__ bfill, uint32* __restrict__ bpack, int nE,
    const float* __restrict__ X, const float* __restrict__ W,
    const float* __restrict__ a_src, const float* __restrict__ a_dst,
    unsigned short* __restrict__ H, float* __restrict__ ALs, float* __restrict__ ALd) {
    __shared__ __align__(16) char smem[33792];
    int tid = threadIdx.x;
    int bid = blockIdx.x;

    if (bid % 3 == 0) {
        // ---- bscatter role (512 threads, EPS=2048 edges), ~20.5KB LDS ----
        int sb = bid / 3;                   // 0..SBLK-1
        int* hist  = (int*)smem;
        int* gbase = hist + 512;
        int* lbase = gbase + 512;
        int* cnt2  = lbase + 512;
        int* wtot  = cnt2 + 512;            // 8
        uint32* lsd = (uint32*)(wtot + 8);  // EPS
        unsigned short* bkt = (unsigned short*)(lsd + EPS);  // EPS shorts

        int lane = tid & 63, wv = tid >> 6;
        int e0 = sb * EPS;
        int e1 = min(e0 + EPS, nE);

        hist[tid] = 0;
        cnt2[tid] = 0;
        __syncthreads();
        for (int e = e0 + tid; e < e1; e += 512) atomicAdd(&hist[dst[e] >> BSH], 1);
        __syncthreads();
        int h = hist[tid];
        int inc = h;
#pragma unroll
        for (int off = 1; off < 64; off <<= 1) {
            int t = __shfl_up(inc, off);
            if (lane >= off) inc += t;
        }
        if (lane == 63) wtot[wv] = inc;
        __syncthreads();
        if (tid < 8) {
            int t = wtot[tid];
#pragma unroll
            for (int off = 1; off < 8; off <<= 1) {
                int u = __shfl_up(t, off, 8);
                if (tid >= off) t += u;
            }
            wtot[tid] = t;
        }
        __syncthreads();
        if (wv > 0) inc += wtot[wv - 1];
        int lb = inc - h;
        lbase[tid] = lb;
        int go = h > 0 ? atomicAdd(&bfill[tid], h) : 0;
        gbase[tid] = tid * BCAP + go - lb;   // g = gbase[b] + slot
        __syncthreads();
        for (int e = e0 + tid; e < e1; e += 512) {
            int s = src[e], dd = dst[e];
            int b = dd >> BSH;
            int r = atomicAdd(&cnt2[b], 1);
            int slot = lbase[b] + r;
            lsd[slot] = ((uint32)s << 8) | (uint32)(dd & 255);
            bkt[slot] = (unsigned short)b;
        }
        __syncthreads();
        int m = e1 - e0;
        for (int i = tid; i < m; i += 512)
            bpack[gbase[bkt[i]] + i] = lsd[i];
    } else {
        // ---- gemm1 role: 64x64 tile, K=128 in two 64-chunks (Xs AND Ws restaged) ----
        const int K = 128, KC = 64, KP = 68;
        float* Xs = (float*)smem;            // 64*68 = 17408B
        float* Ws = Xs + 64 * KP;            // 64*64 chunk = 16384B
        int gb = bid - bid / 3 - 1;          // 0..GB-1
        int r0 = gb * 64;
        int validRows = min(64, NN - r0);

        int cg = tid & 15, rg = tid >> 4;    // rg 0..31
        int rbase = rg * 2;
        float4 acc0 = make_float4(0.f, 0.f, 0.f, 0.f);
        float4 acc1 = acc0;

        const float4* Xg = (const float4*)X;
        const float4* Wg = (const float4*)W;
        const int QG = K / 4;

        for (int kc = 0; kc < K; kc += KC) {
            __syncthreads();
            {
                float4* Ws4 = (float4*)Ws;
                for (int i = tid; i < 1024; i += 512)
                    Ws4[i] = Wg[kc * 16 + i];
            }
            for (int i = tid; i < 1024; i += 512) {
                int row = i >> 4, q = i & 15;
                float4 v = (row < validRows)
                    ? Xg[(size_t)(r0 + row) * QG + (kc >> 2) + q]
                    : make_float4(0.f, 0.f, 0.f, 0.f);
                *(float4*)&Xs[row * KP + q * 4] = v;
            }
            __syncthreads();

#pragma unroll 2
            for (int k = 0; k < KC; k += 4) {
                float4 x0 = *(const float4*)&Xs[(rbase + 0) * KP + k];
                float4 x1 = *(const float4*)&Xs[(rbase + 1) * KP + k];
                float4 w0 = *(const float4*)&Ws[(k + 0) * 64 + 4 * cg];
                float4 w1 = *(const float4*)&Ws[(k + 1) * 64 + 4 * cg];
                float4 w2 = *(const float4*)&Ws[(k + 2) * 64 + 4 * cg];
                float4 w3 = *(const float4*)&Ws[(k + 3) * 64 + 4 * cg];
#define FMA4(A, S, WV) \
                A.x = fmaf(S, WV.x, A.x); A.y = fmaf(S, WV.y, A.y); \
                A.z = fmaf(S, WV.z, A.z); A.w = fmaf(S, WV.w, A.w)
                FMA4(acc0, x0.x, w0); FMA4(acc1, x1.x, w0);
                FMA4(acc0, x0.y, w1); FMA4(acc1, x1.y, w1);
                FMA4(acc0, x0.z, w2); FMA4(acc1, x1.z, w2);
                FMA4(acc0, x0.w, w3); FMA4(acc1, x1.w, w3);
#undef FMA4
            }
        }

        int hh = cg >> 1;
        float4 as4 = ((const float4*)a_src)[cg];
        float4 ad4 = ((const float4*)a_dst)[cg];
        float4 accs[2] = {acc0, acc1};
#pragma unroll
        for (int i = 0; i < 2; ++i) {
            int r = r0 + rbase + i;
            if (r < NN) {
                ushort4 p;
                p.x = f2bf(accs[i].x); p.y = f2bf(accs[i].y);
                p.z = f2bf(accs[i].z); p.w = f2bf(accs[i].w);
                ((ushort4*)H)[(size_t)r * 16 + cg] = p;
                float ps = accs[i].x * as4.x + accs[i].y * as4.y +
                           accs[i].z * as4.z + accs[i].w * as4.w;
                float pd = accs[i].x * ad4.x + accs[i].y * ad4.y +
                           accs[i].z * ad4.z + accs[i].w * ad4.w;
                ps += __shfl_xor(ps, 1);
                pd += __shfl_xor(pd, 1);
                if ((cg & 1) == 0) {
                    ALs[r * 8 + hh] = ps;
                    ALd[r * 8 + hh] = pd;
                }
            }
        }
    }
}

// ---------------- per-bucket counting sort -> rpe (int2) + col (512 threads) ----------------

__global__ __launch_bounds__(512) void bsort_kernel(
    const uint32* __restrict__ bpack, const int* __restrict__ bfill,
    int2* __restrict__ rpe, int* __restrict__ col) {
    __shared__ int cnt[256], cnt2[256];
    __shared__ int wtot[4];
    __shared__ int stage[CAPS];
    int b = blockIdx.x;
    int tid = threadIdx.x;
    int ebeg = b * BCAP;
    int sz = bfill[b];
    int n0 = b << BSH;
    int nn = min(256, NN - n0);

    if (tid < 256) { cnt[tid] = 0; cnt2[tid] = 0; }
    __syncthreads();
    const uint4* bq = (const uint4*)(bpack + ebeg);
    int nq = sz >> 2;
    for (int i = tid; i < nq; i += 512) {
        uint4 p = bq[i];
        atomicAdd(&cnt[p.x & 255u], 1);
        atomicAdd(&cnt[p.y & 255u], 1);
        atomicAdd(&cnt[p.z & 255u], 1);
        atomicAdd(&cnt[p.w & 255u], 1);
    }
    for (int e = (nq << 2) + tid; e < sz; e += 512)
        atomicAdd(&cnt[bpack[ebeg + e] & 255u], 1);
    __syncthreads();
    int lane = tid & 63, wv = tid >> 6;
    int c = (tid < 256) ? cnt[tid] : 0;
    int inc = c;
#pragma unroll
    for (int off = 1; off < 64; off <<= 1) {
        int t = __shfl_up(inc, off);
        if (lane >= off) inc += t;
    }
    if (tid < 256 && lane == 63) wtot[wv] = inc;
    __syncthreads();
    if (tid < 4) {
        int t = wtot[tid];
#pragma unroll
        for (int off = 1; off < 4; off <<= 1) {
            int u = __shfl_up(t, off, 4);
            if (tid >= off) t += u;
        }
        wtot[tid] = t;
    }
    __syncthreads();
    if (tid < 256) {
        if (wv > 0) inc += wtot[wv - 1];
        int excl = inc - c;
        cnt[tid] = excl;
        if (tid < nn) {
            rpe[n0 + tid] = make_int2(ebeg + excl, ebeg + inc);
        }
    }
    __syncthreads();
    bool fits = sz <= CAPS;
    for (int i = tid; i < nq; i += 512) {
        uint4 p = bq[i];
        int d0 = (int)(p.x & 255u), d1 = (int)(p.y & 255u);
        int d2 = (int)(p.z & 255u), d3 = (int)(p.w & 255u);
        int p0 = cnt[d0] + atomicAdd(&cnt2[d0], 1);
        int p1 = cnt[d1] + atomicAdd(&cnt2[d1], 1);
        int p2 = cnt[d2] + atomicAdd(&cnt2[d2], 1);
        int p3 = cnt[d3] + atomicAdd(&cnt2[d3], 1);
        if (fits) {
            stage[p0] = (int)(p.x >> 8); stage[p1] = (int)(p.y >> 8);
            stage[p2] = (int)(p.z >> 8); stage[p3] = (int)(p.w >> 8);
        } else {
            col[ebeg + p0] = (int)(p.x >> 8); col[ebeg + p1] = (int)(p.y >> 8);
            col[ebeg + p2] = (int)(p.z >> 8); col[ebeg + p3] = (int)(p.w >> 8);
        }
    }
    for (int e = (nq << 2) + tid; e < sz; e += 512) {
        uint32 p = bpack[ebeg + e];
        int dl = (int)(p & 255u);
        int pos = cnt[dl] + atomicAdd(&cnt2[dl], 1);
        if (fits) stage[pos] = (int)(p >> 8);
        else col[ebeg + pos] = (int)(p >> 8);
    }
    __syncthreads();
    if (fits) {
        uint4* colq = (uint4*)(col + ebeg);
        const uint4* stq = (const uint4*)stage;
        for (int i = tid; i < nq; i += 512) colq[i] = stq[i];
        for (int i = (nq << 2) + tid; i < sz; i += 512) col[ebeg + i] = stage[i];
    }
}

// ---------------- agg gather loop (R3-proven), fp32 result to LDS row ----------------
// Wave = 4 nodes x (2 edge-lanes x 8 heads). Writes ELU(bias + agg) as 8 f32
// to out8 when (active && epar==0). No block-level sync anywhere inside.

__device__ __forceinline__ void agg_to_lds(
    const uint4* __restrict__ Hq, const float* __restrict__ ALs,
    const float* __restrict__ ALd, const int2* __restrict__ rpe,
    const int* __restrict__ col, const float* __restrict__ bias,
    int d, int head, int epar, bool active, float* __restrict__ out8) {
    float ad = ALd[d * 8 + head];
    float acc0 = 0.f, acc1 = 0.f, acc2 = 0.f, acc3 = 0.f;
    float acc4 = 0.f, acc5 = 0.f, acc6 = 0.f, acc7 = 0.f;
    float wsum = 0.f;

#define FMA8(U, W) { \
    acc0 = fmaf(W, __uint_as_float((U).x << 16), acc0); \
    acc1 = fmaf(W, __uint_as_float((U).x & 0xffff0000u), acc1); \
    acc2 = fmaf(W, __uint_as_float((U).y << 16), acc2); \
    acc3 = fmaf(W, __uint_as_float((U).y & 0xffff0000u), acc3); \
    acc4 = fmaf(W, __uint_as_float((U).z << 16), acc4); \
    acc5 = fmaf(W, __uint_as_float((U).z & 0xffff0000u), acc5); \
    acc6 = fmaf(W, __uint_as_float((U).w << 16), acc6); \
    acc7 = fmaf(W, __uint_as_float((U).w & 0xffff0000u), acc7); }

    if (epar == 0) {   // self loop on even lane group only
        uint4 u = Hq[(size_t)d * 8 + head];
        float e = ALs[d * 8 + head] + ad;
        e = fmaxf(e, 0.2f * e);
        float w = __expf(e);
        FMA8(u, w);
        wsum = w;
    }

    int2 kk = rpe[d];
    int k = kk.x + epar, kend = kk.y;
    for (; k + 6 < kend; k += 8) {
        int s0 = __builtin_nontemporal_load(&col[k]);
        int s1 = __builtin_nontemporal_load(&col[k + 2]);
        int s2 = __builtin_nontemporal_load(&col[k + 4]);
        int s3 = __builtin_nontemporal_load(&col[k + 6]);
        uint4 u0 = Hq[(size_t)s0 * 8 + head];
        uint4 u1 = Hq[(size_t)s1 * 8 + head];
        uint4 u2 = Hq[(size_t)s2 * 8 + head];
        uint4 u3 = Hq[(size_t)s3 * 8 + head];
        float a0 = ALs[s0 * 8 + head];
        float a1 = ALs[s1 * 8 + head];
        float a2 = ALs[s2 * 8 + head];
        float a3 = ALs[s3 * 8 + head];
        float e0 = a0 + ad; e0 = fmaxf(e0, 0.2f * e0); float w0 = __expf(e0);
        float e1 = a1 + ad; e1 = fmaxf(e1, 0.2f * e1); float w1 = __expf(e1);
        float e2 = a2 + ad; e2 = fmaxf(e2, 0.2f * e2); float w2 = __expf(e2);
        float e3 = a3 + ad; e3 = fmaxf(e3, 0.2f * e3); float w3 = __expf(e3);
        FMA8(u0, w0);
        FMA8(u1, w1);
        FMA8(u2, w2);
        FMA8(u3, w3);
        wsum += (w0 + w1) + (w2 + w3);
    }
    if (k + 2 < kend) {
        int s0 = __builtin_nontemporal_load(&col[k]);
        int s1 = __builtin_nontemporal_load(&col[k + 2]);
        uint4 u0 = Hq[(size_t)s0 * 8 + head];
        uint4 u1 = Hq[(size_t)s1 * 8 + head];
        float a0 = ALs[s0 * 8 + head];
        float a1 = ALs[s1 * 8 + head];
        float e0 = a0 + ad; e0 = fmaxf(e0, 0.2f * e0); float w0 = __expf(e0);
        float e1 = a1 + ad; e1 = fmaxf(e1, 0.2f * e1); float w1 = __expf(e1);
        FMA8(u0, w0);
        FMA8(u1, w1);
        wsum += w0 + w1;
        k += 4;
    }
    if (k < kend) {
        int s = __builtin_nontemporal_load(&col[k]);
        uint4 u = Hq[(size_t)s * 8 + head];
        float a = ALs[s * 8 + head];
        float e = a + ad; e = fmaxf(e, 0.2f * e);
        float w = __expf(e);
        FMA8(u, w);
        wsum += w;
    }
#undef FMA8

    // combine the edge-parallel pair (lanes differ in bit 3)
    wsum += __shfl_xor(wsum, 8);
    acc0 += __shfl_xor(acc0, 8);
    acc1 += __shfl_xor(acc1, 8);
    acc2 += __shfl_xor(acc2, 8);
    acc3 += __shfl_xor(acc3, 8);
    acc4 += __shfl_xor(acc4, 8);
    acc5 += __shfl_xor(acc5, 8);
    acc6 += __shfl_xor(acc6, 8);
    acc7 += __shfl_xor(acc7, 8);

    if (active && epar == 0) {
        float inv = 1.f / wsum;
        float4 b0 = ((const float4*)bias)[head * 2];
        float4 b1 = ((const float4*)bias)[head * 2 + 1];
        float4 o0, o1;
        o0.x = fmaf(acc0, inv, b0.x); o0.x = o0.x > 0.f ? o0.x : expm1f(o0.x);
        o0.y = fmaf(acc1, inv, b0.y); o0.y = o0.y > 0.f ? o0.y : expm1f(o0.y);
        o0.z = fmaf(acc2, inv, b0.z); o0.z = o0.z > 0.f ? o0.z : expm1f(o0.z);
        o0.w = fmaf(acc3, inv, b0.w); o0.w = o0.w > 0.f ? o0.w : expm1f(o0.w);
        o1.x = fmaf(acc4, inv, b1.x); o1.x = o1.x > 0.f ? o1.x : expm1f(o1.x);
        o1.y = fmaf(acc5, inv, b1.y); o1.y = o1.y > 0.f ? o1.y : expm1f(o1.y);
        o1.z = fmaf(acc6, inv, b1.z); o1.z = o1.z > 0.f ? o1.z : expm1f(o1.z);
        o1.w = fmaf(acc7, inv, b1.w); o1.w = o1.w > 0.f ? o1.w : expm1f(o1.w);
        ((float4*)out8)[0] = o0;
        ((float4*)out8)[1] = o1;
    }
}

// ---------------- fused agg(L) + WAVE-LOCAL gemm(W_{l+1}), 16 nodes/block ----------------
// Single barrier BEFORE the gather (W staging only — all waves aligned, cheap).
// After the gather each wave reads back only ITS 4x64 LDS slice: same-wave LDS
// RAW is in-order, so no barrier on the divergent path. Waves retire freely.

__global__ __launch_bounds__(256, 6) void aggemm_kernel(
    const unsigned short* __restrict__ H, const float* __restrict__ ALs,
    const float* __restrict__ ALd, const int2* __restrict__ rpe,
    const int* __restrict__ col, const float* __restrict__ bias,
    const float* __restrict__ Wn, const float* __restrict__ ansrc,
    const float* __restrict__ andst, unsigned short* __restrict__ Hout,
    float* __restrict__ ALsOut, float* __restrict__ ALdOut, int n) {
    const int KP = 68;
    __shared__ float Ws[64 * 64];        // 16KB next-layer weight
    __shared__ float Xs[4][4 * KP];      // per-wave 4x64 fp32 slice (4.35KB)
    int tid = threadIdx.x;

    {   // stage W, then ONE barrier before any divergent work
        const float4* Wg = (const float4*)Wn;
        float4* Ws4 = (float4*)Ws;
        for (int i = tid; i < 1024; i += 256) Ws4[i] = Wg[i];
    }
    __syncthreads();

    int lane = tid & 63, wv = tid >> 6;
    int slot = lane >> 4;
    int epar = (lane >> 3) & 1;
    int head = lane & 7;
    int r0 = blockIdx.x * 16;
    int d = r0 + wv * 4 + slot;          // NN = 16*6250: always < n
    agg_to_lds((const uint4*)H, ALs, ALd, rpe, col, bias,
               d, head, epar, true, &Xs[wv][slot * KP + head * 8]);

    // wave-local gemm: 4 rows x 64 cols; lane = (grow = lane>>4, cg = lane&15)
    int cg = lane & 15, grow = lane >> 4;
    const float* xr = &Xs[wv][grow * KP];
    float4 acc = make_float4(0.f, 0.f, 0.f, 0.f);
#pragma unroll
    for (int k = 0; k < 64; k += 4) {
        float4 xv = *(const float4*)&xr[k];
        float4 w0 = *(const float4*)&Ws[(k + 0) * 64 + 4 * cg];
        float4 w1 = *(const float4*)&Ws[(k + 1) * 64 + 4 * cg];
        float4 w2 = *(const float4*)&Ws[(k + 2) * 64 + 4 * cg];
        float4 w3 = *(const float4*)&Ws[(k + 3) * 64 + 4 * cg];
        acc.x = fmaf(xv.x, w0.x, acc.x); acc.y = fmaf(xv.x, w0.y, acc.y);
        acc.z = fmaf(xv.x, w0.z, acc.z); acc.w = fmaf(xv.x, w0.w, acc.w);
        acc.x = fmaf(xv.y, w1.x, acc.x); acc.y = fmaf(xv.y, w1.y, acc.y);
        acc.z = fmaf(xv.y, w1.z, acc.z); acc.w = fmaf(xv.y, w1.w, acc.w);
        acc.x = fmaf(xv.z, w2.x, acc.x); acc.y = fmaf(xv.z, w2.y, acc.y);
        acc.z = fmaf(xv.z, w2.z, acc.z); acc.w = fmaf(xv.z, w2.w, acc.w);
        acc.x = fmaf(xv.w, w3.x, acc.x); acc.y = fmaf(xv.w, w3.y, acc.y);
        acc.z = fmaf(xv.w, w3.z, acc.z); acc.w = fmaf(xv.w, w3.w, acc.w);
    }

    int r = r0 + wv * 4 + grow;
    {
        ushort4 p;
        p.x = f2bf(acc.x); p.y = f2bf(acc.y);
        p.z = f2bf(acc.z); p.w = f2bf(acc.w);
        ((ushort4*)Hout)[(size_t)r * 16 + cg] = p;
        float4 as4 = ((const float4*)ansrc)[cg];
        float4 ad4 = ((const float4*)andst)[cg];
        float ps = acc.x * as4.x + acc.y * as4.y + acc.z * as4.z + acc.w * as4.w;
        float pd = acc.x * ad4.x + acc.y * ad4.y + acc.z * ad4.z + acc.w * ad4.w;
        ps += __shfl_xor(ps, 1);
        pd += __shfl_xor(pd, 1);
        if ((cg & 1) == 0) {
            int hh = cg >> 1;
            ALsOut[r * 8 + hh] = ps;
            ALdOut[r * 8 + hh] = pd;
        }
    }
}

// ---------------- fused agg(L3) + WAVE-LOCAL pool — zero barriers ----------------

__global__ __launch_bounds__(256, 6) void aggpool_kernel(
    const unsigned short* __restrict__ H, const float* __restrict__ ALs,
    const float* __restrict__ ALd, const int2* __restrict__ rpe,
    const int* __restrict__ col, const float* __restrict__ bias,
    const int* __restrict__ batch, float* __restrict__ sums,
    float* __restrict__ gcnt, int n) {
    const int KP = 68;
    __shared__ float Xs[4][4 * KP];
    int tid = threadIdx.x;

    int lane = tid & 63, wv = tid >> 6;
    int slot = lane >> 4;
    int epar = (lane >> 3) & 1;
    int head = lane & 7;
    int r0 = blockIdx.x * 16;
    int d = r0 + wv * 4 + slot;          // NN = 16*6250: always < n
    agg_to_lds((const uint4*)H, ALs, ALd, rpe, col, bias,
               d, head, epar, true, &Xs[wv][slot * KP + head * 8]);

    // wave-local pool over this wave's 4 sorted nodes: lane = feature
    int r0w = r0 + wv * 4;
    int curb = batch[r0w];
    float loc = 0.f, c = 0.f;
#pragma unroll
    for (int rr = 0; rr < 4; ++rr) {
        int b = batch[r0w + rr];
        if (b != curb) {
            atomicAdd(&sums[curb * 64 + lane], loc);
            if (lane == 0) atomicAdd(&gcnt[curb], c);
            loc = 0.f; c = 0.f; curb = b;
        }
        loc += Xs[wv][rr * KP + lane];
        c += 1.f;
    }
    atomicAdd(&sums[curb * 64 + lane], loc);
    if (lane == 0) atomicAdd(&gcnt[curb], c);
}

__global__ void final_kernel(const float* __restrict__ sums, const float* __restrict__ cnt,
                             const float* __restrict__ W, const float* __restrict__ b,
                             float* __restrict__ out) {
    int t = blockIdx.x * blockDim.x + threadIdx.x;
    if (t >= GG * NCLS) return;
    int g = t / NCLS, k = t % NCLS;
    float c = cnt[g];
    if (c < 1.f) c = 1.f;
    float inv = 1.f / c;
    float acc = b[k];
#pragma unroll
    for (int cc = 0; cc < 64; ++cc)
        acc = fmaf(sums[g * 64 + cc] * inv, W[cc * NCLS + k], acc);
    out[t] = acc;
}

// ---------------- launch ----------------

extern "C" void kernel_launch(void* const* d_in, const int* in_sizes, int n_in,
                              void* d_out, int out_size, void* d_ws, size_t ws_size,
                              hipStream_t stream) {
    const float* x    = (const float*)d_in[0];
    const int*   ei   = (const int*)d_in[1];   // [2,E]: src = ei, dst = ei+EE
    const int*   batch = (const int*)d_in[2];
    const float* W1 = (const float*)d_in[3];
    const float* a1s = (const float*)d_in[4];
    const float* a1d = (const float*)d_in[5];
    const float* b1 = (const float*)d_in[6];
    const float* W2 = (const float*)d_in[7];
    const float* a2s = (const float*)d_in[8];
    const float* a2d = (const float*)d_in[9];
    const float* b2 = (const float*)d_in[10];
    const float* W3 = (const float*)d_in[11];
    const float* a3s = (const float*)d_in[12];
    const float* a3d = (const float*)d_in[13];
    const float* b3 = (const float*)d_in[14];
    const float* linW = (const float*)d_in[15];
    const float* linb = (const float*)d_in[16];
    float* out = (float*)d_out;

    char* ws = (char*)d_ws;
    size_t off = 0;
    auto alloc = [&](size_t bytes) -> void* {
        void* p = ws + off;
        off = (off + bytes + 255) & ~(size_t)255;
        return p;
    };
    // contiguous zero-region: bfill | sums | gcnt  (one memset per replay)
    const size_t ZBYTES = (size_t)NB * 4 + (size_t)GG * 64 * 4 + (size_t)GG * 4;
    char* zr = (char*)alloc(ZBYTES);
    int*   bfill = (int*)zr;
    float* sums  = (float*)(zr + (size_t)NB * 4);
    float* gcnt  = sums + GG * 64;

    unsigned short* hA = (unsigned short*)alloc((size_t)NN * 64 * 2);  // bf16 feats (ping)
    unsigned short* hB = (unsigned short*)alloc((size_t)NN * 64 * 2);  // bf16 feats (pong)
    float* ALsA = (float*)alloc((size_t)NN * 8 * 4);
    float* ALdA = (float*)alloc((size_t)NN * 8 * 4);
    float* ALsB = (float*)alloc((size_t)NN * 8 * 4);
    float* ALdB = (float*)alloc((size_t)NN * 8 * 4);
    int2*  rpe  = (int2*)alloc((size_t)NN * 8);
    uint32* bpack = (uint32*)alloc((size_t)NB * BCAP * 4);
    int*   col  = (int*)alloc((size_t)NB * BCAP * 4);

    hipMemsetAsync(zr, 0, ZBYTES, stream);

    // bscatter || gemm1, roles interleaved by blockIdx%3
    pre_kernel<<<SBLK + GB, 512, 0, stream>>>(ei, ei + EE, bfill, bpack, EE,
                                              x, W1, a1s, a1d, hA, ALsA, ALdA);
    // CSR finalize
    bsort_kernel<<<NB, 512, 0, stream>>>(bpack, bfill, rpe, col);

    const int AB = (NN + 15) / 16;    // 6250 blocks, 16 nodes each

    // layer1 agg + layer2 projection (fused, wave-local)
    aggemm_kernel<<<AB, 256, 0, stream>>>(hA, ALsA, ALdA, rpe, col, b1,
                                          W2, a2s, a2d, hB, ALsB, ALdB, NN);
    // layer2 agg + layer3 projection
    aggemm_kernel<<<AB, 256, 0, stream>>>(hB, ALsB, ALdB, rpe, col, b2,
                                          W3, a3s, a3d, hA, ALsA, ALdA, NN);
    // layer3 agg + wave-local pool
    aggpool_kernel<<<AB, 256, 0, stream>>>(hA, ALsA, ALdA, rpe, col, b3,
                                           batch, sums, gcnt, NN);

    final_kernel<<<3, 256, 0, stream>>>(sums, gcnt, linW, linb, out);
}

// Round 11
// 354.627 us; speedup vs baseline: 1.3900x; 1.3900x over previous
//
#include <hip/hip_runtime.h>
#include <math.h>

#define NN 100000
#define EE 1600000
#define GG 64
#define NCLS 10

#define BSH 8                 // bucket = dst >> 8 (256 nodes per bucket)
#define NB 391                // ceil(NN / 256)
#define BCAP 4608             // fixed bucket capacity (mean 4092, sigma 64 -> 8 sigma)
#define EPS 2048              // edges per block in bscatter role (782 blocks)
#define SBLK 782              // ceil(EE / EPS)
#define CAPS 5120             // bsort LDS staging capacity (ints)
#define GB 1563               // ceil(NN / 64) gemm1 blocks

typedef unsigned int uint32;

__device__ __forceinline__ unsigned short f2bf(float f) {
    unsigned u = __float_as_uint(f);
    unsigned r = (u + 0x7fffu + ((u >> 16) & 1u)) >> 16;   // RNE
    return (unsigned short)r;
}

__device__ __forceinline__ float bf2f(unsigned short h) {
    return __uint_as_float((unsigned)h << 16);
}

// ---------------- bscatter (blockIdx%3==0) || gemm1 K=128 (else), R8-proven ----------------

__global__ __launch_bounds__(512) void pre_kernel(
    const int* __restrict__ src, const int* __restrict__ dst,
    int* __restrict__ bfill, uint32* __restrict__ bpack, int nE,
    const float* __restrict__ X, const float* __restrict__ W,
    const float* __restrict__ a_src, const float* __restrict__ a_dst,
    unsigned short* __restrict__ H, float* __restrict__ ALs, float* __restrict__ ALd) {
    __shared__ __align__(16) char smem[33792];
    int tid = threadIdx.x;
    int bid = blockIdx.x;

    if (bid % 3 == 0) {
        // ---- bscatter role (512 threads, EPS=2048 edges), ~20.5KB LDS ----
        int sb = bid / 3;                   // 0..SBLK-1
        int* hist  = (int*)smem;
        int* gbase = hist + 512;
        int* lbase = gbase + 512;
        int* cnt2  = lbase + 512;
        int* wtot  = cnt2 + 512;            // 8
        uint32* lsd = (uint32*)(wtot + 8);  // EPS
        unsigned short* bkt = (unsigned short*)(lsd + EPS);  // EPS shorts

        int lane = tid & 63, wv = tid >> 6;
        int e0 = sb * EPS;
        int e1 = min(e0 + EPS, nE);

        hist[tid] = 0;
        cnt2[tid] = 0;
        __syncthreads();
        for (int e = e0 + tid; e < e1; e += 512) atomicAdd(&hist[dst[e] >> BSH], 1);
        __syncthreads();
        int h = hist[tid];
        int inc = h;
#pragma unroll
        for (int off = 1; off < 64; off <<= 1) {
            int t = __shfl_up(inc, off);
            if (lane >= off) inc += t;
        }
        if (lane == 63) wtot[wv] = inc;
        __syncthreads();
        if (tid < 8) {
            int t = wtot[tid];
#pragma unroll
            for (int off = 1; off < 8; off <<= 1) {
                int u = __shfl_up(t, off, 8);
                if (tid >= off) t += u;
            }
            wtot[tid] = t;
        }
        __syncthreads();
        if (wv > 0) inc += wtot[wv - 1];
        int lb = inc - h;
        lbase[tid] = lb;
        int go = h > 0 ? atomicAdd(&bfill[tid], h) : 0;
        gbase[tid] = tid * BCAP + go - lb;   // g = gbase[b] + slot
        __syncthreads();
        for (int e = e0 + tid; e < e1; e += 512) {
            int s = src[e], dd = dst[e];
            int b = dd >> BSH;
            int r = atomicAdd(&cnt2[b], 1);
            int slot = lbase[b] + r;
            lsd[slot] = ((uint32)s << 8) | (uint32)(dd & 255);
            bkt[slot] = (unsigned short)b;
        }
        __syncthreads();
        int m = e1 - e0;
        for (int i = tid; i < m; i += 512)
            bpack[gbase[bkt[i]] + i] = lsd[i];
    } else {
        // ---- gemm1 role: 64x64 tile, K=128 in two 64-chunks (Xs AND Ws restaged) ----
        const int K = 128, KC = 64, KP = 68;
        float* Xs = (float*)smem;            // 64*68 = 17408B
        float* Ws = Xs + 64 * KP;            // 64*64 chunk = 16384B
        int gb = bid - bid / 3 - 1;          // 0..GB-1
        int r0 = gb * 64;
        int validRows = min(64, NN - r0);

        int cg = tid & 15, rg = tid >> 4;    // rg 0..31
        int rbase = rg * 2;
        float4 acc0 = make_float4(0.f, 0.f, 0.f, 0.f);
        float4 acc1 = acc0;

        const float4* Xg = (const float4*)X;
        const float4* Wg = (const float4*)W;
        const int QG = K / 4;

        for (int kc = 0; kc < K; kc += KC) {
            __syncthreads();
            {
                float4* Ws4 = (float4*)Ws;
                for (int i = tid; i < 1024; i += 512)
                    Ws4[i] = Wg[kc * 16 + i];
            }
            for (int i = tid; i < 1024; i += 512) {
                int row = i >> 4, q = i & 15;
                float4 v = (row < validRows)
                    ? Xg[(size_t)(r0 + row) * QG + (kc >> 2) + q]
                    : make_float4(0.f, 0.f, 0.f, 0.f);
                *(float4*)&Xs[row * KP + q * 4] = v;
            }
            __syncthreads();

#pragma unroll 2
            for (int k = 0; k < KC; k += 4) {
                float4 x0 = *(const float4*)&Xs[(rbase + 0) * KP + k];
                float4 x1 = *(const float4*)&Xs[(rbase + 1) * KP + k];
                float4 w0 = *(const float4*)&Ws[(k + 0) * 64 + 4 * cg];
                float4 w1 = *(const float4*)&Ws[(k + 1) * 64 + 4 * cg];
                float4 w2 = *(const float4*)&Ws[(k + 2) * 64 + 4 * cg];
                float4 w3 = *(const float4*)&Ws[(k + 3) * 64 + 4 * cg];
#define FMA4(A, S, WV) \
                A.x = fmaf(S, WV.x, A.x); A.y = fmaf(S, WV.y, A.y); \
                A.z = fmaf(S, WV.z, A.z); A.w = fmaf(S, WV.w, A.w)
                FMA4(acc0, x0.x, w0); FMA4(acc1, x1.x, w0);
                FMA4(acc0, x0.y, w1); FMA4(acc1, x1.y, w1);
                FMA4(acc0, x0.z, w2); FMA4(acc1, x1.z, w2);
                FMA4(acc0, x0.w, w3); FMA4(acc1, x1.w, w3);
#undef FMA4
            }
        }

        int hh = cg >> 1;
        float4 as4 = ((const float4*)a_src)[cg];
        float4 ad4 = ((const float4*)a_dst)[cg];
        float4 accs[2] = {acc0, acc1};
#pragma unroll
        for (int i = 0; i < 2; ++i) {
            int r = r0 + rbase + i;
            if (r < NN) {
                ushort4 p;
                p.x = f2bf(accs[i].x); p.y = f2bf(accs[i].y);
                p.z = f2bf(accs[i].z); p.w = f2bf(accs[i].w);
                ((ushort4*)H)[(size_t)r * 16 + cg] = p;
                float ps = accs[i].x * as4.x + accs[i].y * as4.y +
                           accs[i].z * as4.z + accs[i].w * as4.w;
                float pd = accs[i].x * ad4.x + accs[i].y * ad4.y +
                           accs[i].z * ad4.z + accs[i].w * ad4.w;
                ps += __shfl_xor(ps, 1);
                pd += __shfl_xor(pd, 1);
                if ((cg & 1) == 0) {
                    ALs[r * 8 + hh] = ps;
                    ALd[r * 8 + hh] = pd;
                }
            }
        }
    }
}

// ---------------- per-bucket counting sort -> rpe (int2) + col (512 threads) ----------------

__global__ __launch_bounds__(512) void bsort_kernel(
    const uint32* __restrict__ bpack, const int* __restrict__ bfill,
    int2* __restrict__ rpe, int* __restrict__ col) {
    __shared__ int cnt[256], cnt2[256];
    __shared__ int wtot[4];
    __shared__ int stage[CAPS];
    int b = blockIdx.x;
    int tid = threadIdx.x;
    int ebeg = b * BCAP;
    int sz = bfill[b];
    int n0 = b << BSH;
    int nn = min(256, NN - n0);

    if (tid < 256) { cnt[tid] = 0; cnt2[tid] = 0; }
    __syncthreads();
    const uint4* bq = (const uint4*)(bpack + ebeg);
    int nq = sz >> 2;
    for (int i = tid; i < nq; i += 512) {
        uint4 p = bq[i];
        atomicAdd(&cnt[p.x & 255u], 1);
        atomicAdd(&cnt[p.y & 255u], 1);
        atomicAdd(&cnt[p.z & 255u], 1);
        atomicAdd(&cnt[p.w & 255u], 1);
    }
    for (int e = (nq << 2) + tid; e < sz; e += 512)
        atomicAdd(&cnt[bpack[ebeg + e] & 255u], 1);
    __syncthreads();
    int lane = tid & 63, wv = tid >> 6;
    int c = (tid < 256) ? cnt[tid] : 0;
    int inc = c;
#pragma unroll
    for (int off = 1; off < 64; off <<= 1) {
        int t = __shfl_up(inc, off);
        if (lane >= off) inc += t;
    }
    if (tid < 256 && lane == 63) wtot[wv] = inc;
    __syncthreads();
    if (tid < 4) {
        int t = wtot[tid];
#pragma unroll
        for (int off = 1; off < 4; off <<= 1) {
            int u = __shfl_up(t, off, 4);
            if (tid >= off) t += u;
        }
        wtot[tid] = t;
    }
    __syncthreads();
    if (tid < 256) {
        if (wv > 0) inc += wtot[wv - 1];
        int excl = inc - c;
        cnt[tid] = excl;
        if (tid < nn) {
            rpe[n0 + tid] = make_int2(ebeg + excl, ebeg + inc);
        }
    }
    __syncthreads();
    bool fits = sz <= CAPS;
    for (int i = tid; i < nq; i += 512) {
        uint4 p = bq[i];
        int d0 = (int)(p.x & 255u), d1 = (int)(p.y & 255u);
        int d2 = (int)(p.z & 255u), d3 = (int)(p.w & 255u);
        int p0 = cnt[d0] + atomicAdd(&cnt2[d0], 1);
        int p1 = cnt[d1] + atomicAdd(&cnt2[d1], 1);
        int p2 = cnt[d2] + atomicAdd(&cnt2[d2], 1);
        int p3 = cnt[d3] + atomicAdd(&cnt2[d3], 1);
        if (fits) {
            stage[p0] = (int)(p.x >> 8); stage[p1] = (int)(p.y >> 8);
            stage[p2] = (int)(p.z >> 8); stage[p3] = (int)(p.w >> 8);
        } else {
            col[ebeg + p0] = (int)(p.x >> 8); col[ebeg + p1] = (int)(p.y >> 8);
            col[ebeg + p2] = (int)(p.z >> 8); col[ebeg + p3] = (int)(p.w >> 8);
        }
    }
    for (int e = (nq << 2) + tid; e < sz; e += 512) {
        uint32 p = bpack[ebeg + e];
        int dl = (int)(p & 255u);
        int pos = cnt[dl] + atomicAdd(&cnt2[dl], 1);
        if (fits) stage[pos] = (int)(p >> 8);
        else col[ebeg + pos] = (int)(p >> 8);
    }
    __syncthreads();
    if (fits) {
        uint4* colq = (uint4*)(col + ebeg);
        const uint4* stq = (const uint4*)stage;
        for (int i = tid; i < nq; i += 512) colq[i] = stq[i];
        for (int i = (nq << 2) + tid; i < sz; i += 512) col[ebeg + i] = stage[i];
    }
}

// ---------------- agg gather loop (R3-proven), fp32 result to LDS row ----------------

__device__ __forceinline__ void agg_to_lds(
    const uint4* __restrict__ Hq, const float* __restrict__ ALs,
    const float* __restrict__ ALd, const int2* __restrict__ rpe,
    const int* __restrict__ col, const float* __restrict__ bias,
    int d, int head, int epar, bool active, float* __restrict__ out8) {
    float ad = ALd[d * 8 + head];
    float acc0 = 0.f, acc1 = 0.f, acc2 = 0.f, acc3 = 0.f;
    float acc4 = 0.f, acc5 = 0.f, acc6 = 0.f, acc7 = 0.f;
    float wsum = 0.f;

#define FMA8(U, W) { \
    acc0 = fmaf(W, __uint_as_float((U).x << 16), acc0); \
    acc1 = fmaf(W, __uint_as_float((U).x & 0xffff0000u), acc1); \
    acc2 = fmaf(W, __uint_as_float((U).y << 16), acc2); \
    acc3 = fmaf(W, __uint_as_float((U).y & 0xffff0000u), acc3); \
    acc4 = fmaf(W, __uint_as_float((U).z << 16), acc4); \
    acc5 = fmaf(W, __uint_as_float((U).z & 0xffff0000u), acc5); \
    acc6 = fmaf(W, __uint_as_float((U).w << 16), acc6); \
    acc7 = fmaf(W, __uint_as_float((U).w & 0xffff0000u), acc7); }

    if (epar == 0) {   // self loop on even lane group only
        uint4 u = Hq[(size_t)d * 8 + head];
        float e = ALs[d * 8 + head] + ad;
        e = fmaxf(e, 0.2f * e);
        float w = __expf(e);
        FMA8(u, w);
        wsum = w;
    }

    int2 kk = rpe[d];
    int k = kk.x + epar, kend = kk.y;
    for (; k + 6 < kend; k += 8) {
        int s0 = __builtin_nontemporal_load(&col[k]);
        int s1 = __builtin_nontemporal_load(&col[k + 2]);
        int s2 = __builtin_nontemporal_load(&col[k + 4]);
        int s3 = __builtin_nontemporal_load(&col[k + 6]);
        uint4 u0 = Hq[(size_t)s0 * 8 + head];
        uint4 u1 = Hq[(size_t)s1 * 8 + head];
        uint4 u2 = Hq[(size_t)s2 * 8 + head];
        uint4 u3 = Hq[(size_t)s3 * 8 + head];
        float a0 = ALs[s0 * 8 + head];
        float a1 = ALs[s1 * 8 + head];
        float a2 = ALs[s2 * 8 + head];
        float a3 = ALs[s3 * 8 + head];
        float e0 = a0 + ad; e0 = fmaxf(e0, 0.2f * e0); float w0 = __expf(e0);
        float e1 = a1 + ad; e1 = fmaxf(e1, 0.2f * e1); float w1 = __expf(e1);
        float e2 = a2 + ad; e2 = fmaxf(e2, 0.2f * e2); float w2 = __expf(e2);
        float e3 = a3 + ad; e3 = fmaxf(e3, 0.2f * e3); float w3 = __expf(e3);
        FMA8(u0, w0);
        FMA8(u1, w1);
        FMA8(u2, w2);
        FMA8(u3, w3);
        wsum += (w0 + w1) + (w2 + w3);
    }
    if (k + 2 < kend) {
        int s0 = __builtin_nontemporal_load(&col[k]);
        int s1 = __builtin_nontemporal_load(&col[k + 2]);
        uint4 u0 = Hq[(size_t)s0 * 8 + head];
        uint4 u1 = Hq[(size_t)s1 * 8 + head];
        float a0 = ALs[s0 * 8 + head];
        float a1 = ALs[s1 * 8 + head];
        float e0 = a0 + ad; e0 = fmaxf(e0, 0.2f * e0); float w0 = __expf(e0);
        float e1 = a1 + ad; e1 = fmaxf(e1, 0.2f * e1); float w1 = __expf(e1);
        FMA8(u0, w0);
        FMA8(u1, w1);
        wsum += w0 + w1;
        k += 4;
    }
    if (k < kend) {
        int s = __builtin_nontemporal_load(&col[k]);
        uint4 u = Hq[(size_t)s * 8 + head];
        float a = ALs[s * 8 + head];
        float e = a + ad; e = fmaxf(e, 0.2f * e);
        float w = __expf(e);
        FMA8(u, w);
        wsum += w;
    }
#undef FMA8

    // combine the edge-parallel pair (lanes differ in bit 3)
    wsum += __shfl_xor(wsum, 8);
    acc0 += __shfl_xor(acc0, 8);
    acc1 += __shfl_xor(acc1, 8);
    acc2 += __shfl_xor(acc2, 8);
    acc3 += __shfl_xor(acc3, 8);
    acc4 += __shfl_xor(acc4, 8);
    acc5 += __shfl_xor(acc5, 8);
    acc6 += __shfl_xor(acc6, 8);
    acc7 += __shfl_xor(acc7, 8);

    if (active && epar == 0) {
        float inv = 1.f / wsum;
        float4 b0 = ((const float4*)bias)[head * 2];
        float4 b1 = ((const float4*)bias)[head * 2 + 1];
        float4 o0, o1;
        o0.x = fmaf(acc0, inv, b0.x); o0.x = o0.x > 0.f ? o0.x : expm1f(o0.x);
        o0.y = fmaf(acc1, inv, b0.y); o0.y = o0.y > 0.f ? o0.y : expm1f(o0.y);
        o0.z = fmaf(acc2, inv, b0.z); o0.z = o0.z > 0.f ? o0.z : expm1f(o0.z);
        o0.w = fmaf(acc3, inv, b0.w); o0.w = o0.w > 0.f ? o0.w : expm1f(o0.w);
        o1.x = fmaf(acc4, inv, b1.x); o1.x = o1.x > 0.f ? o1.x : expm1f(o1.x);
        o1.y = fmaf(acc5, inv, b1.y); o1.y = o1.y > 0.f ? o1.y : expm1f(o1.y);
        o1.z = fmaf(acc6, inv, b1.z); o1.z = o1.z > 0.f ? o1.z : expm1f(o1.z);
        o1.w = fmaf(acc7, inv, b1.w); o1.w = o1.w > 0.f ? o1.w : expm1f(o1.w);
        ((float4*)out8)[0] = o0;
        ((float4*)out8)[1] = o1;
    }
}

// ---------------- fused agg(L) + gemm(W_{l+1}) + next-layer AL, 16 nodes/block ----------------
// R9-proven (64us in the 358 pipeline). Block barrier after gather; GEMM row-local.

__global__ __launch_bounds__(256, 6) void aggemm_kernel(
    const unsigned short* __restrict__ H, const float* __restrict__ ALs,
    const float* __restrict__ ALd, const int2* __restrict__ rpe,
    const int* __restrict__ col, const float* __restrict__ bias,
    const float* __restrict__ Wn, const float* __restrict__ ansrc,
    const float* __restrict__ andst, unsigned short* __restrict__ Hout,
    float* __restrict__ ALsOut, float* __restrict__ ALdOut, int n) {
    const int KP = 68;
    __shared__ float Xs[16 * KP];     // 4.35KB fp32 agg outputs
    __shared__ float Ws[64 * 64];     // 16KB next-layer weight
    int tid = threadIdx.x;

    {   // stage W (L2-resident; loads overlap gather issue)
        const float4* Wg = (const float4*)Wn;
        float4* Ws4 = (float4*)Ws;
        for (int i = tid; i < 1024; i += 256) Ws4[i] = Wg[i];
    }

    int lane = tid & 63;
    int slot = lane >> 4;
    int epar = (lane >> 3) & 1;
    int head = lane & 7;
    int r0 = blockIdx.x * 16;
    int row = (tid >> 6) * 4 + slot;
    int d = r0 + row;
    bool active = d < n;
    if (!active) d = n - 1;

    agg_to_lds((const uint4*)H, ALs, ALd, rpe, col, bias,
               d, head, epar, active, &Xs[row * KP + head * 8]);
    __syncthreads();

    // gemm: 16 rows x 64 cols from LDS; thread = (row, 4-col group)
    int cg = tid & 15, grow = tid >> 4;
    float4 acc = make_float4(0.f, 0.f, 0.f, 0.f);
#pragma unroll 4
    for (int k = 0; k < 64; k += 4) {
        float x0 = Xs[grow * KP + k + 0];
        float x1 = Xs[grow * KP + k + 1];
        float x2 = Xs[grow * KP + k + 2];
        float x3 = Xs[grow * KP + k + 3];
        float4 w0 = *(const float4*)&Ws[(k + 0) * 64 + 4 * cg];
        float4 w1 = *(const float4*)&Ws[(k + 1) * 64 + 4 * cg];
        float4 w2 = *(const float4*)&Ws[(k + 2) * 64 + 4 * cg];
        float4 w3 = *(const float4*)&Ws[(k + 3) * 64 + 4 * cg];
        acc.x = fmaf(x0, w0.x, acc.x); acc.y = fmaf(x0, w0.y, acc.y);
        acc.z = fmaf(x0, w0.z, acc.z); acc.w = fmaf(x0, w0.w, acc.w);
        acc.x = fmaf(x1, w1.x, acc.x); acc.y = fmaf(x1, w1.y, acc.y);
        acc.z = fmaf(x1, w1.z, acc.z); acc.w = fmaf(x1, w1.w, acc.w);
        acc.x = fmaf(x2, w2.x, acc.x); acc.y = fmaf(x2, w2.y, acc.y);
        acc.z = fmaf(x2, w2.z, acc.z); acc.w = fmaf(x2, w2.w, acc.w);
        acc.x = fmaf(x3, w3.x, acc.x); acc.y = fmaf(x3, w3.y, acc.y);
        acc.z = fmaf(x3, w3.z, acc.z); acc.w = fmaf(x3, w3.w, acc.w);
    }

    int r = r0 + grow;
    if (r < n) {
        ushort4 p;
        p.x = f2bf(acc.x); p.y = f2bf(acc.y);
        p.z = f2bf(acc.z); p.w = f2bf(acc.w);
        ((ushort4*)Hout)[(size_t)r * 16 + cg] = p;
        float4 as4 = ((const float4*)ansrc)[cg];
        float4 ad4 = ((const float4*)andst)[cg];
        float ps = acc.x * as4.x + acc.y * as4.y + acc.z * as4.z + acc.w * as4.w;
        float pd = acc.x * ad4.x + acc.y * ad4.y + acc.z * ad4.z + acc.w * ad4.w;
        ps += __shfl_xor(ps, 1);
        pd += __shfl_xor(pd, 1);
        if ((cg & 1) == 0) {
            int hh = cg >> 1;
            ALsOut[r * 8 + hh] = ps;
            ALdOut[r * 8 + hh] = pd;
        }
    }
}

// ---------------- standalone agg (layer 3): bf16 out — R8-proven (52us) ----------------

__global__ __launch_bounds__(256, 6) void agg_kernel(
    const unsigned short* __restrict__ H, const float* __restrict__ ALs,
    const float* __restrict__ ALd, const int2* __restrict__ rpe,
    const int* __restrict__ col,
    const float* __restrict__ bias, unsigned short* __restrict__ Out, int n) {
    int tid = threadIdx.x;
    int lane = tid & 63;
    int slot = lane >> 4;            // 4 nodes per wave
    int epar = (lane >> 3) & 1;      // 2 edge-parallel lanes per node
    int head = lane & 7;
    int wid = blockIdx.x * 4 + (tid >> 6);
    int d = wid * 4 + slot;
    bool active = d < n;
    if (!active) d = n - 1;
    const uint4* __restrict__ Hq = (const uint4*)H;   // row = 8 uint4

    float ad = ALd[d * 8 + head];
    float acc0 = 0.f, acc1 = 0.f, acc2 = 0.f, acc3 = 0.f;
    float acc4 = 0.f, acc5 = 0.f, acc6 = 0.f, acc7 = 0.f;
    float wsum = 0.f;

#define FMA8(U, W) { \
    acc0 = fmaf(W, __uint_as_float((U).x << 16), acc0); \
    acc1 = fmaf(W, __uint_as_float((U).x & 0xffff0000u), acc1); \
    acc2 = fmaf(W, __uint_as_float((U).y << 16), acc2); \
    acc3 = fmaf(W, __uint_as_float((U).y & 0xffff0000u), acc3); \
    acc4 = fmaf(W, __uint_as_float((U).z << 16), acc4); \
    acc5 = fmaf(W, __uint_as_float((U).z & 0xffff0000u), acc5); \
    acc6 = fmaf(W, __uint_as_float((U).w << 16), acc6); \
    acc7 = fmaf(W, __uint_as_float((U).w & 0xffff0000u), acc7); }

    if (epar == 0) {   // self loop on even lane group only
        uint4 u = Hq[(size_t)d * 8 + head];
        float e = ALs[d * 8 + head] + ad;
        e = fmaxf(e, 0.2f * e);
        float w = __expf(e);
        FMA8(u, w);
        wsum = w;
    }

    int2 kk = rpe[d];
    int k = kk.x + epar, kend = kk.y;
    for (; k + 6 < kend; k += 8) {
        int s0 = __builtin_nontemporal_load(&col[k]);
        int s1 = __builtin_nontemporal_load(&col[k + 2]);
        int s2 = __builtin_nontemporal_load(&col[k + 4]);
        int s3 = __builtin_nontemporal_load(&col[k + 6]);
        uint4 u0 = Hq[(size_t)s0 * 8 + head];
        uint4 u1 = Hq[(size_t)s1 * 8 + head];
        uint4 u2 = Hq[(size_t)s2 * 8 + head];
        uint4 u3 = Hq[(size_t)s3 * 8 + head];
        float a0 = ALs[s0 * 8 + head];
        float a1 = ALs[s1 * 8 + head];
        float a2 = ALs[s2 * 8 + head];
        float a3 = ALs[s3 * 8 + head];
        float e0 = a0 + ad; e0 = fmaxf(e0, 0.2f * e0); float w0 = __expf(e0);
        float e1 = a1 + ad; e1 = fmaxf(e1, 0.2f * e1); float w1 = __expf(e1);
        float e2 = a2 + ad; e2 = fmaxf(e2, 0.2f * e2); float w2 = __expf(e2);
        float e3 = a3 + ad; e3 = fmaxf(e3, 0.2f * e3); float w3 = __expf(e3);
        FMA8(u0, w0);
        FMA8(u1, w1);
        FMA8(u2, w2);
        FMA8(u3, w3);
        wsum += (w0 + w1) + (w2 + w3);
    }
    if (k + 2 < kend) {   // 2-edge step
        int s0 = __builtin_nontemporal_load(&col[k]);
        int s1 = __builtin_nontemporal_load(&col[k + 2]);
        uint4 u0 = Hq[(size_t)s0 * 8 + head];
        uint4 u1 = Hq[(size_t)s1 * 8 + head];
        float a0 = ALs[s0 * 8 + head];
        float a1 = ALs[s1 * 8 + head];
        float e0 = a0 + ad; e0 = fmaxf(e0, 0.2f * e0); float w0 = __expf(e0);
        float e1 = a1 + ad; e1 = fmaxf(e1, 0.2f * e1); float w1 = __expf(e1);
        FMA8(u0, w0);
        FMA8(u1, w1);
        wsum += w0 + w1;
        k += 4;
    }
    if (k < kend) {
        int s = __builtin_nontemporal_load(&col[k]);
        uint4 u = Hq[(size_t)s * 8 + head];
        float a = ALs[s * 8 + head];
        float e = a + ad; e = fmaxf(e, 0.2f * e);
        float w = __expf(e);
        FMA8(u, w);
        wsum += w;
    }
#undef FMA8

    // combine the edge-parallel pair (lanes differ in bit 3)
    wsum += __shfl_xor(wsum, 8);
    acc0 += __shfl_xor(acc0, 8);
    acc1 += __shfl_xor(acc1, 8);
    acc2 += __shfl_xor(acc2, 8);
    acc3 += __shfl_xor(acc3, 8);
    acc4 += __shfl_xor(acc4, 8);
    acc5 += __shfl_xor(acc5, 8);
    acc6 += __shfl_xor(acc6, 8);
    acc7 += __shfl_xor(acc7, 8);

    if (active && epar == 0) {
        float inv = 1.f / wsum;
        float4 b0 = ((const float4*)bias)[head * 2];
        float4 b1 = ((const float4*)bias)[head * 2 + 1];
        float o0, o1, o2, o3, o4, o5, o6, o7;
        o0 = fmaf(acc0, inv, b0.x); o0 = o0 > 0.f ? o0 : expm1f(o0);
        o1 = fmaf(acc1, inv, b0.y); o1 = o1 > 0.f ? o1 : expm1f(o1);
        o2 = fmaf(acc2, inv, b0.z); o2 = o2 > 0.f ? o2 : expm1f(o2);
        o3 = fmaf(acc3, inv, b0.w); o3 = o3 > 0.f ? o3 : expm1f(o3);
        o4 = fmaf(acc4, inv, b1.x); o4 = o4 > 0.f ? o4 : expm1f(o4);
        o5 = fmaf(acc5, inv, b1.y); o5 = o5 > 0.f ? o5 : expm1f(o5);
        o6 = fmaf(acc6, inv, b1.z); o6 = o6 > 0.f ? o6 : expm1f(o6);
        o7 = fmaf(acc7, inv, b1.w); o7 = o7 > 0.f ? o7 : expm1f(o7);
        uint4 pk;
        pk.x = (uint32)f2bf(o0) | ((uint32)f2bf(o1) << 16);
        pk.y = (uint32)f2bf(o2) | ((uint32)f2bf(o3) << 16);
        pk.z = (uint32)f2bf(o4) | ((uint32)f2bf(o5) << 16);
        pk.w = (uint32)f2bf(o6) | ((uint32)f2bf(o7) << 16);
        ((uint4*)Out)[(size_t)d * 8 + head] = pk;   // row = 64 bf16 = 8 uint4
    }
}

// ---------------- global mean pool: wave = 8 nodes x 8 lanes, uint4 loads — R7-proven ------

__global__ __launch_bounds__(256) void pool_kernel(
    const unsigned short* __restrict__ H, const int* __restrict__ batch,
    float* __restrict__ sums, float* __restrict__ gcnt, int n) {
    int tid = threadIdx.x;
    int lane = tid & 63;
    int fl = lane & 7;       // feat group: feats [fl*8, fl*8+8)
    int slot = lane >> 3;    // node slot within 8-group
    int w = blockIdx.x * 4 + (tid >> 6);
    int n0 = w * 32;
    if (n0 >= n) return;
    const uint4* Hq = (const uint4*)H;

    float a0 = 0.f, a1 = 0.f, a2 = 0.f, a3 = 0.f;
    float a4 = 0.f, a5 = 0.f, a6 = 0.f, a7 = 0.f;
    int cntacc = 0, bacc = -1;

#define FLUSH() { \
    float t0 = a0, t1 = a1, t2 = a2, t3 = a3, t4 = a4, t5 = a5, t6 = a6, t7 = a7; \
    float tc = (float)cntacc; \
    t0 += __shfl_xor(t0, 8);  t1 += __shfl_xor(t1, 8);  t2 += __shfl_xor(t2, 8);  t3 += __shfl_xor(t3, 8); \
    t4 += __shfl_xor(t4, 8);  t5 += __shfl_xor(t5, 8);  t6 += __shfl_xor(t6, 8);  t7 += __shfl_xor(t7, 8); \
    tc += __shfl_xor(tc, 8); \
    t0 += __shfl_xor(t0, 16); t1 += __shfl_xor(t1, 16); t2 += __shfl_xor(t2, 16); t3 += __shfl_xor(t3, 16); \
    t4 += __shfl_xor(t4, 16); t5 += __shfl_xor(t5, 16); t6 += __shfl_xor(t6, 16); t7 += __shfl_xor(t7, 16); \
    tc += __shfl_xor(tc, 16); \
    t0 += __shfl_xor(t0, 32); t1 += __shfl_xor(t1, 32); t2 += __shfl_xor(t2, 32); t3 += __shfl_xor(t3, 32); \
    t4 += __shfl_xor(t4, 32); t5 += __shfl_xor(t5, 32); t6 += __shfl_xor(t6, 32); t7 += __shfl_xor(t7, 32); \
    tc += __shfl_xor(tc, 32); \
    if (slot == 0) { \
        float* sg = &sums[bacc * 64 + fl * 8]; \
        atomicAdd(&sg[0], t0); atomicAdd(&sg[1], t1); atomicAdd(&sg[2], t2); atomicAdd(&sg[3], t3); \
        atomicAdd(&sg[4], t4); atomicAdd(&sg[5], t5); atomicAdd(&sg[6], t6); atomicAdd(&sg[7], t7); \
        if (fl == 0) atomicAdd(&gcnt[bacc], tc); \
    } }

#pragma unroll
    for (int it = 0; it < 4; ++it) {
        int node = n0 + it * 8 + slot;       // NN % 32 == 0: always valid
        int b = batch[node];
        uint4 v = Hq[(size_t)node * 8 + fl];
        float f0 = bf2f((unsigned short)(v.x & 0xffffu));
        float f1 = bf2f((unsigned short)(v.x >> 16));
        float f2 = bf2f((unsigned short)(v.y & 0xffffu));
        float f3 = bf2f((unsigned short)(v.y >> 16));
        float f4 = bf2f((unsigned short)(v.z & 0xffffu));
        float f5 = bf2f((unsigned short)(v.z >> 16));
        float f6 = bf2f((unsigned short)(v.w & 0xffffu));
        float f7 = bf2f((unsigned short)(v.w >> 16));
        bool uni = __all(b == __shfl(b, 0)) != 0;
        if (uni && b == bacc) {
            a0 += f0; a1 += f1; a2 += f2; a3 += f3;
            a4 += f4; a5 += f5; a6 += f6; a7 += f7;
            cntacc++;
        } else {
            if (cntacc > 0) FLUSH();
            if (uni) {
                bacc = b;
                a0 = f0; a1 = f1; a2 = f2; a3 = f3;
                a4 = f4; a5 = f5; a6 = f6; a7 = f7;
                cntacc = 1;
            } else {
                // rare: 8-node group spans a graph boundary -> per-lane atomics
                float* sg = &sums[b * 64 + fl * 8];
                atomicAdd(&sg[0], f0); atomicAdd(&sg[1], f1);
                atomicAdd(&sg[2], f2); atomicAdd(&sg[3], f3);
                atomicAdd(&sg[4], f4); atomicAdd(&sg[5], f5);
                atomicAdd(&sg[6], f6); atomicAdd(&sg[7], f7);
                if (fl == 0) atomicAdd(&gcnt[b], 1.f);
                bacc = -1;
                cntacc = 0;
            }
        }
    }
    if (cntacc > 0) FLUSH();
#undef FLUSH
}

__global__ void final_kernel(const float* __restrict__ sums, const float* __restrict__ cnt,
                             const float* __restrict__ W, const float* __restrict__ b,
                             float* __restrict__ out) {
    int t = blockIdx.x * blockDim.x + threadIdx.x;
    if (t >= GG * NCLS) return;
    int g = t / NCLS, k = t % NCLS;
    float c = cnt[g];
    if (c < 1.f) c = 1.f;
    float inv = 1.f / c;
    float acc = b[k];
#pragma unroll
    for (int cc = 0; cc < 64; ++cc)
        acc = fmaf(sums[g * 64 + cc] * inv, W[cc * NCLS + k], acc);
    out[t] = acc;
}

// ---------------- launch ----------------

extern "C" void kernel_launch(void* const* d_in, const int* in_sizes, int n_in,
                              void* d_out, int out_size, void* d_ws, size_t ws_size,
                              hipStream_t stream) {
    const float* x    = (const float*)d_in[0];
    const int*   ei   = (const int*)d_in[1];   // [2,E]: src = ei, dst = ei+EE
    const int*   batch = (const int*)d_in[2];
    const float* W1 = (const float*)d_in[3];
    const float* a1s = (const float*)d_in[4];
    const float* a1d = (const float*)d_in[5];
    const float* b1 = (const float*)d_in[6];
    const float* W2 = (const float*)d_in[7];
    const float* a2s = (const float*)d_in[8];
    const float* a2d = (const float*)d_in[9];
    const float* b2 = (const float*)d_in[10];
    const float* W3 = (const float*)d_in[11];
    const float* a3s = (const float*)d_in[12];
    const float* a3d = (const float*)d_in[13];
    const float* b3 = (const float*)d_in[14];
    const float* linW = (const float*)d_in[15];
    const float* linb = (const float*)d_in[16];
    float* out = (float*)d_out;

    char* ws = (char*)d_ws;
    size_t off = 0;
    auto alloc = [&](size_t bytes) -> void* {
        void* p = ws + off;
        off = (off + bytes + 255) & ~(size_t)255;
        return p;
    };
    // contiguous zero-region: bfill | sums | gcnt  (one memset per replay)
    const size_t ZBYTES = (size_t)NB * 4 + (size_t)GG * 64 * 4 + (size_t)GG * 4;
    char* zr = (char*)alloc(ZBYTES);
    int*   bfill = (int*)zr;
    float* sums  = (float*)(zr + (size_t)NB * 4);
    float* gcnt  = sums + GG * 64;

    unsigned short* hA = (unsigned short*)alloc((size_t)NN * 64 * 2);  // bf16 feats (ping)
    unsigned short* hB = (unsigned short*)alloc((size_t)NN * 64 * 2);  // bf16 feats (pong)
    float* ALsA = (float*)alloc((size_t)NN * 8 * 4);
    float* ALdA = (float*)alloc((size_t)NN * 8 * 4);
    float* ALsB = (float*)alloc((size_t)NN * 8 * 4);
    float* ALdB = (float*)alloc((size_t)NN * 8 * 4);
    int2*  rpe  = (int2*)alloc((size_t)NN * 8);
    uint32* bpack = (uint32*)alloc((size_t)NB * BCAP * 4);
    int*   col  = (int*)alloc((size_t)NB * BCAP * 4);

    hipMemsetAsync(zr, 0, ZBYTES, stream);

    // bscatter || gemm1, roles interleaved by blockIdx%3
    pre_kernel<<<SBLK + GB, 512, 0, stream>>>(ei, ei + EE, bfill, bpack, EE,
                                              x, W1, a1s, a1d, hA, ALsA, ALdA);
    // CSR finalize
    bsort_kernel<<<NB, 512, 0, stream>>>(bpack, bfill, rpe, col);

    const int AB = (NN + 15) / 16;    // 6250 blocks, 16 nodes each

    // layer1 agg + layer2 projection (fused, block-local, R9-proven)
    aggemm_kernel<<<AB, 256, 0, stream>>>(hA, ALsA, ALdA, rpe, col, b1,
                                          W2, a2s, a2d, hB, ALsB, ALdB, NN);
    // layer2 agg + layer3 projection
    aggemm_kernel<<<AB, 256, 0, stream>>>(hB, ALsB, ALdB, rpe, col, b2,
                                          W3, a3s, a3d, hA, ALsA, ALdA, NN);
    // layer3 agg (standalone, bf16 out) + split pool + final
    agg_kernel<<<AB, 256, 0, stream>>>(hA, ALsA, ALdA, rpe, col, b3, hB, NN);

    const int PB = ((NN + 31) / 32 + 3) / 4;   // 782 blocks
    pool_kernel<<<PB, 256, 0, stream>>>(hB, batch, sums, gcnt, NN);
    final_kernel<<<3, 256, 0, stream>>>(sums, gcnt, linW, linb, out);
}

// Round 12
// 354.116 us; speedup vs baseline: 1.3920x; 1.0014x over previous
//
#include <hip/hip_runtime.h>
#include <math.h>

#define NN 100000
#define EE 1600000
#define GG 64
#define NCLS 10

#define BSH 8                 // bucket = dst >> 8 (256 nodes per bucket)
#define NB 391                // ceil(NN / 256)
#define BCAP 4608             // fixed bucket capacity (mean 4092, sigma 64 -> 8 sigma)
#define EPS 4096              // edges per bscatter-role block (391 blocks, 1:4 interleave)
#define SBLK 391              // ceil(EE / EPS)
#define CAPS 5120             // bsort LDS staging capacity (ints)
#define GB 1563               // ceil(NN / 64) gemm1 blocks

typedef unsigned int uint32;

__device__ __forceinline__ unsigned short f2bf(float f) {
    unsigned u = __float_as_uint(f);
    unsigned r = (u + 0x7fffu + ((u >> 16) & 1u)) >> 16;   // RNE
    return (unsigned short)r;
}

__device__ __forceinline__ float bf2f(unsigned short h) {
    return __uint_as_float((unsigned)h << 16);
}

// ---------------- bscatter (blockIdx%5==0) || gemm1 K=128 (else) ----------------
// 1:4 role interleave keeps both pipes busy on every CU (R8-proven pattern);
// EPS=4096 halves bscatter block count -> better hist/scan amortization.

__global__ __launch_bounds__(512) void pre_kernel(
    const int* __restrict__ src, const int* __restrict__ dst,
    int* __restrict__ bfill, uint32* __restrict__ bpack, int nE,
    const float* __restrict__ X, const float* __restrict__ W,
    const float* __restrict__ a_src, const float* __restrict__ a_dst,
    unsigned short* __restrict__ H, float* __restrict__ ALs, float* __restrict__ ALd) {
    __shared__ __align__(16) char smem[33792];
    int tid = threadIdx.x;
    int bid = blockIdx.x;

    if (bid % 5 == 0) {
        // ---- bscatter role (512 threads, EPS=4096 edges), ~32.8KB LDS ----
        int sb = bid / 5;                   // 0..SBLK-1
        int* hist  = (int*)smem;
        int* gbase = hist + 512;
        int* lbase = gbase + 512;
        int* cnt2  = lbase + 512;
        int* wtot  = cnt2 + 512;            // 8
        uint32* lsd = (uint32*)(wtot + 8);  // EPS
        unsigned short* bkt = (unsigned short*)(lsd + EPS);  // EPS shorts

        int lane = tid & 63, wv = tid >> 6;
        int e0 = sb * EPS;
        int e1 = min(e0 + EPS, nE);

        hist[tid] = 0;
        cnt2[tid] = 0;
        __syncthreads();
        for (int e = e0 + tid; e < e1; e += 512) atomicAdd(&hist[dst[e] >> BSH], 1);
        __syncthreads();
        int h = hist[tid];
        int inc = h;
#pragma unroll
        for (int off = 1; off < 64; off <<= 1) {
            int t = __shfl_up(inc, off);
            if (lane >= off) inc += t;
        }
        if (lane == 63) wtot[wv] = inc;
        __syncthreads();
        if (tid < 8) {
            int t = wtot[tid];
#pragma unroll
            for (int off = 1; off < 8; off <<= 1) {
                int u = __shfl_up(t, off, 8);
                if (tid >= off) t += u;
            }
            wtot[tid] = t;
        }
        __syncthreads();
        if (wv > 0) inc += wtot[wv - 1];
        int lb = inc - h;
        lbase[tid] = lb;
        int go = h > 0 ? atomicAdd(&bfill[tid], h) : 0;
        gbase[tid] = tid * BCAP + go - lb;   // g = gbase[b] + slot
        __syncthreads();
        for (int e = e0 + tid; e < e1; e += 512) {
            int s = src[e], dd = dst[e];
            int b = dd >> BSH;
            int r = atomicAdd(&cnt2[b], 1);
            int slot = lbase[b] + r;
            lsd[slot] = ((uint32)s << 8) | (uint32)(dd & 255);
            bkt[slot] = (unsigned short)b;
        }
        __syncthreads();
        int m = e1 - e0;
        for (int i = tid; i < m; i += 512)
            bpack[gbase[bkt[i]] + i] = lsd[i];
    } else {
        // ---- gemm1 role: 64x64 tile, K=128 in two 64-chunks (Xs AND Ws restaged) ----
        const int K = 128, KC = 64, KP = 68;
        float* Xs = (float*)smem;            // 64*68 = 17408B
        float* Ws = Xs + 64 * KP;            // 64*64 chunk = 16384B
        int gb = bid - bid / 5 - 1;          // 0..GB-1
        int r0 = gb * 64;
        int validRows = min(64, NN - r0);

        int cg = tid & 15, rg = tid >> 4;    // rg 0..31
        int rbase = rg * 2;
        float4 acc0 = make_float4(0.f, 0.f, 0.f, 0.f);
        float4 acc1 = acc0;

        const float4* Xg = (const float4*)X;
        const float4* Wg = (const float4*)W;
        const int QG = K / 4;

        for (int kc = 0; kc < K; kc += KC) {
            __syncthreads();
            {
                float4* Ws4 = (float4*)Ws;
                for (int i = tid; i < 1024; i += 512)
                    Ws4[i] = Wg[kc * 16 + i];
            }
            for (int i = tid; i < 1024; i += 512) {
                int row = i >> 4, q = i & 15;
                float4 v = (row < validRows)
                    ? Xg[(size_t)(r0 + row) * QG + (kc >> 2) + q]
                    : make_float4(0.f, 0.f, 0.f, 0.f);
                *(float4*)&Xs[row * KP + q * 4] = v;
            }
            __syncthreads();

#pragma unroll 2
            for (int k = 0; k < KC; k += 4) {
                float4 x0 = *(const float4*)&Xs[(rbase + 0) * KP + k];
                float4 x1 = *(const float4*)&Xs[(rbase + 1) * KP + k];
                float4 w0 = *(const float4*)&Ws[(k + 0) * 64 + 4 * cg];
                float4 w1 = *(const float4*)&Ws[(k + 1) * 64 + 4 * cg];
                float4 w2 = *(const float4*)&Ws[(k + 2) * 64 + 4 * cg];
                float4 w3 = *(const float4*)&Ws[(k + 3) * 64 + 4 * cg];
#define FMA4(A, S, WV) \
                A.x = fmaf(S, WV.x, A.x); A.y = fmaf(S, WV.y, A.y); \
                A.z = fmaf(S, WV.z, A.z); A.w = fmaf(S, WV.w, A.w)
                FMA4(acc0, x0.x, w0); FMA4(acc1, x1.x, w0);
                FMA4(acc0, x0.y, w1); FMA4(acc1, x1.y, w1);
                FMA4(acc0, x0.z, w2); FMA4(acc1, x1.z, w2);
                FMA4(acc0, x0.w, w3); FMA4(acc1, x1.w, w3);
#undef FMA4
            }
        }

        int hh = cg >> 1;
        float4 as4 = ((const float4*)a_src)[cg];
        float4 ad4 = ((const float4*)a_dst)[cg];
        float4 accs[2] = {acc0, acc1};
#pragma unroll
        for (int i = 0; i < 2; ++i) {
            int r = r0 + rbase + i;
            if (r < NN) {
                ushort4 p;
                p.x = f2bf(accs[i].x); p.y = f2bf(accs[i].y);
                p.z = f2bf(accs[i].z); p.w = f2bf(accs[i].w);
                ((ushort4*)H)[(size_t)r * 16 + cg] = p;
                float ps = accs[i].x * as4.x + accs[i].y * as4.y +
                           accs[i].z * as4.z + accs[i].w * as4.w;
                float pd = accs[i].x * ad4.x + accs[i].y * ad4.y +
                           accs[i].z * ad4.z + accs[i].w * ad4.w;
                ps += __shfl_xor(ps, 1);
                pd += __shfl_xor(pd, 1);
                if ((cg & 1) == 0) {
                    ALs[r * 8 + hh] = ps;
                    ALd[r * 8 + hh] = pd;
                }
            }
        }
    }
}

// ---------------- per-bucket counting sort -> rpe (int2) + col (1024 threads) --------------
// Grid is 391 blocks (1.5/CU) -> per-block latency IS kernel time; 1024 threads
// halve the serial per-block work vs 512.

__global__ __launch_bounds__(1024) void bsort_kernel(
    const uint32* __restrict__ bpack, const int* __restrict__ bfill,
    int2* __restrict__ rpe, int* __restrict__ col) {
    __shared__ int cnt[256], cnt2[256];
    __shared__ int wtot[4];
    __shared__ int stage[CAPS];
    int b = blockIdx.x;
    int tid = threadIdx.x;
    int ebeg = b * BCAP;
    int sz = bfill[b];
    int n0 = b << BSH;
    int nn = min(256, NN - n0);

    if (tid < 256) { cnt[tid] = 0; cnt2[tid] = 0; }
    __syncthreads();
    const uint4* bq = (const uint4*)(bpack + ebeg);
    int nq = sz >> 2;
    for (int i = tid; i < nq; i += 1024) {
        uint4 p = bq[i];
        atomicAdd(&cnt[p.x & 255u], 1);
        atomicAdd(&cnt[p.y & 255u], 1);
        atomicAdd(&cnt[p.z & 255u], 1);
        atomicAdd(&cnt[p.w & 255u], 1);
    }
    for (int e = (nq << 2) + tid; e < sz; e += 1024)
        atomicAdd(&cnt[bpack[ebeg + e] & 255u], 1);
    __syncthreads();
    int lane = tid & 63, wv = tid >> 6;
    int c = (tid < 256) ? cnt[tid] : 0;
    int inc = c;
#pragma unroll
    for (int off = 1; off < 64; off <<= 1) {
        int t = __shfl_up(inc, off);
        if (lane >= off) inc += t;
    }
    if (tid < 256 && lane == 63) wtot[wv] = inc;
    __syncthreads();
    if (tid < 4) {
        int t = wtot[tid];
#pragma unroll
        for (int off = 1; off < 4; off <<= 1) {
            int u = __shfl_up(t, off, 4);
            if (tid >= off) t += u;
        }
        wtot[tid] = t;
    }
    __syncthreads();
    if (tid < 256) {
        if (wv > 0) inc += wtot[wv - 1];
        int excl = inc - c;
        cnt[tid] = excl;
        if (tid < nn) {
            rpe[n0 + tid] = make_int2(ebeg + excl, ebeg + inc);
        }
    }
    __syncthreads();
    bool fits = sz <= CAPS;
    for (int i = tid; i < nq; i += 1024) {
        uint4 p = bq[i];
        int d0 = (int)(p.x & 255u), d1 = (int)(p.y & 255u);
        int d2 = (int)(p.z & 255u), d3 = (int)(p.w & 255u);
        int p0 = cnt[d0] + atomicAdd(&cnt2[d0], 1);
        int p1 = cnt[d1] + atomicAdd(&cnt2[d1], 1);
        int p2 = cnt[d2] + atomicAdd(&cnt2[d2], 1);
        int p3 = cnt[d3] + atomicAdd(&cnt2[d3], 1);
        if (fits) {
            stage[p0] = (int)(p.x >> 8); stage[p1] = (int)(p.y >> 8);
            stage[p2] = (int)(p.z >> 8); stage[p3] = (int)(p.w >> 8);
        } else {
            col[ebeg + p0] = (int)(p.x >> 8); col[ebeg + p1] = (int)(p.y >> 8);
            col[ebeg + p2] = (int)(p.z >> 8); col[ebeg + p3] = (int)(p.w >> 8);
        }
    }
    for (int e = (nq << 2) + tid; e < sz; e += 1024) {
        uint32 p = bpack[ebeg + e];
        int dl = (int)(p & 255u);
        int pos = cnt[dl] + atomicAdd(&cnt2[dl], 1);
        if (fits) stage[pos] = (int)(p >> 8);
        else col[ebeg + pos] = (int)(p >> 8);
    }
    __syncthreads();
    if (fits) {
        uint4* colq = (uint4*)(col + ebeg);
        const uint4* stq = (const uint4*)stage;
        for (int i = tid; i < nq; i += 1024) colq[i] = stq[i];
        for (int i = (nq << 2) + tid; i < sz; i += 1024) col[ebeg + i] = stage[i];
    }
}

// ---------------- agg gather loop (R3-proven), fp32 result to LDS row ----------------

__device__ __forceinline__ void agg_to_lds(
    const uint4* __restrict__ Hq, const float* __restrict__ ALs,
    const float* __restrict__ ALd, const int2* __restrict__ rpe,
    const int* __restrict__ col, const float* __restrict__ bias,
    int d, int head, int epar, bool active, float* __restrict__ out8) {
    float ad = ALd[d * 8 + head];
    float acc0 = 0.f, acc1 = 0.f, acc2 = 0.f, acc3 = 0.f;
    float acc4 = 0.f, acc5 = 0.f, acc6 = 0.f, acc7 = 0.f;
    float wsum = 0.f;

#define FMA8(U, W) { \
    acc0 = fmaf(W, __uint_as_float((U).x << 16), acc0); \
    acc1 = fmaf(W, __uint_as_float((U).x & 0xffff0000u), acc1); \
    acc2 = fmaf(W, __uint_as_float((U).y << 16), acc2); \
    acc3 = fmaf(W, __uint_as_float((U).y & 0xffff0000u), acc3); \
    acc4 = fmaf(W, __uint_as_float((U).z << 16), acc4); \
    acc5 = fmaf(W, __uint_as_float((U).z & 0xffff0000u), acc5); \
    acc6 = fmaf(W, __uint_as_float((U).w << 16), acc6); \
    acc7 = fmaf(W, __uint_as_float((U).w & 0xffff0000u), acc7); }

    if (epar == 0) {   // self loop on even lane group only
        uint4 u = Hq[(size_t)d * 8 + head];
        float e = ALs[d * 8 + head] + ad;
        e = fmaxf(e, 0.2f * e);
        float w = __expf(e);
        FMA8(u, w);
        wsum = w;
    }

    int2 kk = rpe[d];
    int k = kk.x + epar, kend = kk.y;
    for (; k + 6 < kend; k += 8) {
        int s0 = __builtin_nontemporal_load(&col[k]);
        int s1 = __builtin_nontemporal_load(&col[k + 2]);
        int s2 = __builtin_nontemporal_load(&col[k + 4]);
        int s3 = __builtin_nontemporal_load(&col[k + 6]);
        uint4 u0 = Hq[(size_t)s0 * 8 + head];
        uint4 u1 = Hq[(size_t)s1 * 8 + head];
        uint4 u2 = Hq[(size_t)s2 * 8 + head];
        uint4 u3 = Hq[(size_t)s3 * 8 + head];
        float a0 = ALs[s0 * 8 + head];
        float a1 = ALs[s1 * 8 + head];
        float a2 = ALs[s2 * 8 + head];
        float a3 = ALs[s3 * 8 + head];
        float e0 = a0 + ad; e0 = fmaxf(e0, 0.2f * e0); float w0 = __expf(e0);
        float e1 = a1 + ad; e1 = fmaxf(e1, 0.2f * e1); float w1 = __expf(e1);
        float e2 = a2 + ad; e2 = fmaxf(e2, 0.2f * e2); float w2 = __expf(e2);
        float e3 = a3 + ad; e3 = fmaxf(e3, 0.2f * e3); float w3 = __expf(e3);
        FMA8(u0, w0);
        FMA8(u1, w1);
        FMA8(u2, w2);
        FMA8(u3, w3);
        wsum += (w0 + w1) + (w2 + w3);
    }
    if (k + 2 < kend) {
        int s0 = __builtin_nontemporal_load(&col[k]);
        int s1 = __builtin_nontemporal_load(&col[k + 2]);
        uint4 u0 = Hq[(size_t)s0 * 8 + head];
        uint4 u1 = Hq[(size_t)s1 * 8 + head];
        float a0 = ALs[s0 * 8 + head];
        float a1 = ALs[s1 * 8 + head];
        float e0 = a0 + ad; e0 = fmaxf(e0, 0.2f * e0); float w0 = __expf(e0);
        float e1 = a1 + ad; e1 = fmaxf(e1, 0.2f * e1); float w1 = __expf(e1);
        FMA8(u0, w0);
        FMA8(u1, w1);
        wsum += w0 + w1;
        k += 4;
    }
    if (k < kend) {
        int s = __builtin_nontemporal_load(&col[k]);
        uint4 u = Hq[(size_t)s * 8 + head];
        float a = ALs[s * 8 + head];
        float e = a + ad; e = fmaxf(e, 0.2f * e);
        float w = __expf(e);
        FMA8(u, w);
        wsum += w;
    }
#undef FMA8

    // combine the edge-parallel pair (lanes differ in bit 3)
    wsum += __shfl_xor(wsum, 8);
    acc0 += __shfl_xor(acc0, 8);
    acc1 += __shfl_xor(acc1, 8);
    acc2 += __shfl_xor(acc2, 8);
    acc3 += __shfl_xor(acc3, 8);
    acc4 += __shfl_xor(acc4, 8);
    acc5 += __shfl_xor(acc5, 8);
    acc6 += __shfl_xor(acc6, 8);
    acc7 += __shfl_xor(acc7, 8);

    if (active && epar == 0) {
        float inv = 1.f / wsum;
        float4 b0 = ((const float4*)bias)[head * 2];
        float4 b1 = ((const float4*)bias)[head * 2 + 1];
        float4 o0, o1;
        o0.x = fmaf(acc0, inv, b0.x); o0.x = o0.x > 0.f ? o0.x : expm1f(o0.x);
        o0.y = fmaf(acc1, inv, b0.y); o0.y = o0.y > 0.f ? o0.y : expm1f(o0.y);
        o0.z = fmaf(acc2, inv, b0.z); o0.z = o0.z > 0.f ? o0.z : expm1f(o0.z);
        o0.w = fmaf(acc3, inv, b0.w); o0.w = o0.w > 0.f ? o0.w : expm1f(o0.w);
        o1.x = fmaf(acc4, inv, b1.x); o1.x = o1.x > 0.f ? o1.x : expm1f(o1.x);
        o1.y = fmaf(acc5, inv, b1.y); o1.y = o1.y > 0.f ? o1.y : expm1f(o1.y);
        o1.z = fmaf(acc6, inv, b1.z); o1.z = o1.z > 0.f ? o1.z : expm1f(o1.z);
        o1.w = fmaf(acc7, inv, b1.w); o1.w = o1.w > 0.f ? o1.w : expm1f(o1.w);
        ((float4*)out8)[0] = o0;
        ((float4*)out8)[1] = o1;
    }
}

// ---------------- fused agg(L) + gemm(W_{l+1}) + next-layer AL, 16 nodes/block ----------------
// R9/R11-proven (65us). Block barrier after gather; GEMM row-local.

__global__ __launch_bounds__(256, 6) void aggemm_kernel(
    const unsigned short* __restrict__ H, const float* __restrict__ ALs,
    const float* __restrict__ ALd, const int2* __restrict__ rpe,
    const int* __restrict__ col, const float* __restrict__ bias,
    const float* __restrict__ Wn, const float* __restrict__ ansrc,
    const float* __restrict__ andst, unsigned short* __restrict__ Hout,
    float* __restrict__ ALsOut, float* __restrict__ ALdOut, int n) {
    const int KP = 68;
    __shared__ float Xs[16 * KP];     // 4.35KB fp32 agg outputs
    __shared__ float Ws[64 * 64];     // 16KB next-layer weight
    int tid = threadIdx.x;

    {   // stage W (L2-resident; loads overlap gather issue)
        const float4* Wg = (const float4*)Wn;
        float4* Ws4 = (float4*)Ws;
        for (int i = tid; i < 1024; i += 256) Ws4[i] = Wg[i];
    }

    int lane = tid & 63;
    int slot = lane >> 4;
    int epar = (lane >> 3) & 1;
    int head = lane & 7;
    int r0 = blockIdx.x * 16;
    int row = (tid >> 6) * 4 + slot;
    int d = r0 + row;
    bool active = d < n;
    if (!active) d = n - 1;

    agg_to_lds((const uint4*)H, ALs, ALd, rpe, col, bias,
               d, head, epar, active, &Xs[row * KP + head * 8]);
    __syncthreads();

    // gemm: 16 rows x 64 cols from LDS; thread = (row, 4-col group)
    int cg = tid & 15, grow = tid >> 4;
    float4 acc = make_float4(0.f, 0.f, 0.f, 0.f);
#pragma unroll 4
    for (int k = 0; k < 64; k += 4) {
        float4 xv = *(const float4*)&Xs[grow * KP + k];
        float4 w0 = *(const float4*)&Ws[(k + 0) * 64 + 4 * cg];
        float4 w1 = *(const float4*)&Ws[(k + 1) * 64 + 4 * cg];
        float4 w2 = *(const float4*)&Ws[(k + 2) * 64 + 4 * cg];
        float4 w3 = *(const float4*)&Ws[(k + 3) * 64 + 4 * cg];
        acc.x = fmaf(xv.x, w0.x, acc.x); acc.y = fmaf(xv.x, w0.y, acc.y);
        acc.z = fmaf(xv.x, w0.z, acc.z); acc.w = fmaf(xv.x, w0.w, acc.w);
        acc.x = fmaf(xv.y, w1.x, acc.x); acc.y = fmaf(xv.y, w1.y, acc.y);
        acc.z = fmaf(xv.y, w1.z, acc.z); acc.w = fmaf(xv.y, w1.w, acc.w);
        acc.x = fmaf(xv.z, w2.x, acc.x); acc.y = fmaf(xv.z, w2.y, acc.y);
        acc.z = fmaf(xv.z, w2.z, acc.z); acc.w = fmaf(xv.z, w2.w, acc.w);
        acc.x = fmaf(xv.w, w3.x, acc.x); acc.y = fmaf(xv.w, w3.y, acc.y);
        acc.z = fmaf(xv.w, w3.z, acc.z); acc.w = fmaf(xv.w, w3.w, acc.w);
    }

    int r = r0 + grow;
    if (r < n) {
        ushort4 p;
        p.x = f2bf(acc.x); p.y = f2bf(acc.y);
        p.z = f2bf(acc.z); p.w = f2bf(acc.w);
        ((ushort4*)Hout)[(size_t)r * 16 + cg] = p;
        float4 as4 = ((const float4*)ansrc)[cg];
        float4 ad4 = ((const float4*)andst)[cg];
        float ps = acc.x * as4.x + acc.y * as4.y + acc.z * as4.z + acc.w * as4.w;
        float pd = acc.x * ad4.x + acc.y * ad4.y + acc.z * ad4.z + acc.w * ad4.w;
        ps += __shfl_xor(ps, 1);
        pd += __shfl_xor(pd, 1);
        if ((cg & 1) == 0) {
            int hh = cg >> 1;
            ALsOut[r * 8 + hh] = ps;
            ALdOut[r * 8 + hh] = pd;
        }
    }
}

// ---------------- standalone agg (layer 3): bf16 out — R8-proven (52us) ----------------

__global__ __launch_bounds__(256, 6) void agg_kernel(
    const unsigned short* __restrict__ H, const float* __restrict__ ALs,
    const float* __restrict__ ALd, const int2* __restrict__ rpe,
    const int* __restrict__ col,
    const float* __restrict__ bias, unsigned short* __restrict__ Out, int n) {
    int tid = threadIdx.x;
    int lane = tid & 63;
    int slot = lane >> 4;            // 4 nodes per wave
    int epar = (lane >> 3) & 1;      // 2 edge-parallel lanes per node
    int head = lane & 7;
    int wid = blockIdx.x * 4 + (tid >> 6);
    int d = wid * 4 + slot;
    bool active = d < n;
    if (!active) d = n - 1;
    const uint4* __restrict__ Hq = (const uint4*)H;   // row = 8 uint4

    float ad = ALd[d * 8 + head];
    float acc0 = 0.f, acc1 = 0.f, acc2 = 0.f, acc3 = 0.f;
    float acc4 = 0.f, acc5 = 0.f, acc6 = 0.f, acc7 = 0.f;
    float wsum = 0.f;

#define FMA8(U, W) { \
    acc0 = fmaf(W, __uint_as_float((U).x << 16), acc0); \
    acc1 = fmaf(W, __uint_as_float((U).x & 0xffff0000u), acc1); \
    acc2 = fmaf(W, __uint_as_float((U).y << 16), acc2); \
    acc3 = fmaf(W, __uint_as_float((U).y & 0xffff0000u), acc3); \
    acc4 = fmaf(W, __uint_as_float((U).z << 16), acc4); \
    acc5 = fmaf(W, __uint_as_float((U).z & 0xffff0000u), acc5); \
    acc6 = fmaf(W, __uint_as_float((U).w << 16), acc6); \
    acc7 = fmaf(W, __uint_as_float((U).w & 0xffff0000u), acc7); }

    if (epar == 0) {   // self loop on even lane group only
        uint4 u = Hq[(size_t)d * 8 + head];
        float e = ALs[d * 8 + head] + ad;
        e = fmaxf(e, 0.2f * e);
        float w = __expf(e);
        FMA8(u, w);
        wsum = w;
    }

    int2 kk = rpe[d];
    int k = kk.x + epar, kend = kk.y;
    for (; k + 6 < kend; k += 8) {
        int s0 = __builtin_nontemporal_load(&col[k]);
        int s1 = __builtin_nontemporal_load(&col[k + 2]);
        int s2 = __builtin_nontemporal_load(&col[k + 4]);
        int s3 = __builtin_nontemporal_load(&col[k + 6]);
        uint4 u0 = Hq[(size_t)s0 * 8 + head];
        uint4 u1 = Hq[(size_t)s1 * 8 + head];
        uint4 u2 = Hq[(size_t)s2 * 8 + head];
        uint4 u3 = Hq[(size_t)s3 * 8 + head];
        float a0 = ALs[s0 * 8 + head];
        float a1 = ALs[s1 * 8 + head];
        float a2 = ALs[s2 * 8 + head];
        float a3 = ALs[s3 * 8 + head];
        float e0 = a0 + ad; e0 = fmaxf(e0, 0.2f * e0); float w0 = __expf(e0);
        float e1 = a1 + ad; e1 = fmaxf(e1, 0.2f * e1); float w1 = __expf(e1);
        float e2 = a2 + ad; e2 = fmaxf(e2, 0.2f * e2); float w2 = __expf(e2);
        float e3 = a3 + ad; e3 = fmaxf(e3, 0.2f * e3); float w3 = __expf(e3);
        FMA8(u0, w0);
        FMA8(u1, w1);
        FMA8(u2, w2);
        FMA8(u3, w3);
        wsum += (w0 + w1) + (w2 + w3);
    }
    if (k + 2 < kend) {   // 2-edge step
        int s0 = __builtin_nontemporal_load(&col[k]);
        int s1 = __builtin_nontemporal_load(&col[k + 2]);
        uint4 u0 = Hq[(size_t)s0 * 8 + head];
        uint4 u1 = Hq[(size_t)s1 * 8 + head];
        float a0 = ALs[s0 * 8 + head];
        float a1 = ALs[s1 * 8 + head];
        float e0 = a0 + ad; e0 = fmaxf(e0, 0.2f * e0); float w0 = __expf(e0);
        float e1 = a1 + ad; e1 = fmaxf(e1, 0.2f * e1); float w1 = __expf(e1);
        FMA8(u0, w0);
        FMA8(u1, w1);
        wsum += w0 + w1;
        k += 4;
    }
    if (k < kend) {
        int s = __builtin_nontemporal_load(&col[k]);
        uint4 u = Hq[(size_t)s * 8 + head];
        float a = ALs[s * 8 + head];
        float e = a + ad; e = fmaxf(e, 0.2f * e);
        float w = __expf(e);
        FMA8(u, w);
        wsum += w;
    }
#undef FMA8

    // combine the edge-parallel pair (lanes differ in bit 3)
    wsum += __shfl_xor(wsum, 8);
    acc0 += __shfl_xor(acc0, 8);
    acc1 += __shfl_xor(acc1, 8);
    acc2 += __shfl_xor(acc2, 8);
    acc3 += __shfl_xor(acc3, 8);
    acc4 += __shfl_xor(acc4, 8);
    acc5 += __shfl_xor(acc5, 8);
    acc6 += __shfl_xor(acc6, 8);
    acc7 += __shfl_xor(acc7, 8);

    if (active && epar == 0) {
        float inv = 1.f / wsum;
        float4 b0 = ((const float4*)bias)[head * 2];
        float4 b1 = ((const float4*)bias)[head * 2 + 1];
        float o0, o1, o2, o3, o4, o5, o6, o7;
        o0 = fmaf(acc0, inv, b0.x); o0 = o0 > 0.f ? o0 : expm1f(o0);
        o1 = fmaf(acc1, inv, b0.y); o1 = o1 > 0.f ? o1 : expm1f(o1);
        o2 = fmaf(acc2, inv, b0.z); o2 = o2 > 0.f ? o2 : expm1f(o2);
        o3 = fmaf(acc3, inv, b0.w); o3 = o3 > 0.f ? o3 : expm1f(o3);
        o4 = fmaf(acc4, inv, b1.x); o4 = o4 > 0.f ? o4 : expm1f(o4);
        o5 = fmaf(acc5, inv, b1.y); o5 = o5 > 0.f ? o5 : expm1f(o5);
        o6 = fmaf(acc6, inv, b1.z); o6 = o6 > 0.f ? o6 : expm1f(o6);
        o7 = fmaf(acc7, inv, b1.w); o7 = o7 > 0.f ? o7 : expm1f(o7);
        uint4 pk;
        pk.x = (uint32)f2bf(o0) | ((uint32)f2bf(o1) << 16);
        pk.y = (uint32)f2bf(o2) | ((uint32)f2bf(o3) << 16);
        pk.z = (uint32)f2bf(o4) | ((uint32)f2bf(o5) << 16);
        pk.w = (uint32)f2bf(o6) | ((uint32)f2bf(o7) << 16);
        ((uint4*)Out)[(size_t)d * 8 + head] = pk;   // row = 64 bf16 = 8 uint4
    }
}

// ---------------- global mean pool: wave = 8 nodes x 8 lanes, uint4 loads — R7-proven ------

__global__ __launch_bounds__(256) void pool_kernel(
    const unsigned short* __restrict__ H, const int* __restrict__ batch,
    float* __restrict__ sums, float* __restrict__ gcnt, int n) {
    int tid = threadIdx.x;
    int lane = tid & 63;
    int fl = lane & 7;       // feat group: feats [fl*8, fl*8+8)
    int slot = lane >> 3;    // node slot within 8-group
    int w = blockIdx.x * 4 + (tid >> 6);
    int n0 = w * 32;
    if (n0 >= n) return;
    const uint4* Hq = (const uint4*)H;

    float a0 = 0.f, a1 = 0.f, a2 = 0.f, a3 = 0.f;
    float a4 = 0.f, a5 = 0.f, a6 = 0.f, a7 = 0.f;
    int cntacc = 0, bacc = -1;

#define FLUSH() { \
    float t0 = a0, t1 = a1, t2 = a2, t3 = a3, t4 = a4, t5 = a5, t6 = a6, t7 = a7; \
    float tc = (float)cntacc; \
    t0 += __shfl_xor(t0, 8);  t1 += __shfl_xor(t1, 8);  t2 += __shfl_xor(t2, 8);  t3 += __shfl_xor(t3, 8); \
    t4 += __shfl_xor(t4, 8);  t5 += __shfl_xor(t5, 8);  t6 += __shfl_xor(t6, 8);  t7 += __shfl_xor(t7, 8); \
    tc += __shfl_xor(tc, 8); \
    t0 += __shfl_xor(t0, 16); t1 += __shfl_xor(t1, 16); t2 += __shfl_xor(t2, 16); t3 += __shfl_xor(t3, 16); \
    t4 += __shfl_xor(t4, 16); t5 += __shfl_xor(t5, 16); t6 += __shfl_xor(t6, 16); t7 += __shfl_xor(t7, 16); \
    tc += __shfl_xor(tc, 16); \
    t0 += __shfl_xor(t0, 32); t1 += __shfl_xor(t1, 32); t2 += __shfl_xor(t2, 32); t3 += __shfl_xor(t3, 32); \
    t4 += __shfl_xor(t4, 32); t5 += __shfl_xor(t5, 32); t6 += __shfl_xor(t6, 32); t7 += __shfl_xor(t7, 32); \
    tc += __shfl_xor(tc, 32); \
    if (slot == 0) { \
        float* sg = &sums[bacc * 64 + fl * 8]; \
        atomicAdd(&sg[0], t0); atomicAdd(&sg[1], t1); atomicAdd(&sg[2], t2); atomicAdd(&sg[3], t3); \
        atomicAdd(&sg[4], t4); atomicAdd(&sg[5], t5); atomicAdd(&sg[6], t6); atomicAdd(&sg[7], t7); \
        if (fl == 0) atomicAdd(&gcnt[bacc], tc); \
    } }

#pragma unroll
    for (int it = 0; it < 4; ++it) {
        int node = n0 + it * 8 + slot;       // NN % 32 == 0: always valid
        int b = batch[node];
        uint4 v = Hq[(size_t)node * 8 + fl];
        float f0 = bf2f((unsigned short)(v.x & 0xffffu));
        float f1 = bf2f((unsigned short)(v.x >> 16));
        float f2 = bf2f((unsigned short)(v.y & 0xffffu));
        float f3 = bf2f((unsigned short)(v.y >> 16));
        float f4 = bf2f((unsigned short)(v.z & 0xffffu));
        float f5 = bf2f((unsigned short)(v.z >> 16));
        float f6 = bf2f((unsigned short)(v.w & 0xffffu));
        float f7 = bf2f((unsigned short)(v.w >> 16));
        bool uni = __all(b == __shfl(b, 0)) != 0;
        if (uni && b == bacc) {
            a0 += f0; a1 += f1; a2 += f2; a3 += f3;
            a4 += f4; a5 += f5; a6 += f6; a7 += f7;
            cntacc++;
        } else {
            if (cntacc > 0) FLUSH();
            if (uni) {
                bacc = b;
                a0 = f0; a1 = f1; a2 = f2; a3 = f3;
                a4 = f4; a5 = f5; a6 = f6; a7 = f7;
                cntacc = 1;
            } else {
                // rare: 8-node group spans a graph boundary -> per-lane atomics
                float* sg = &sums[b * 64 + fl * 8];
                atomicAdd(&sg[0], f0); atomicAdd(&sg[1], f1);
                atomicAdd(&sg[2], f2); atomicAdd(&sg[3], f3);
                atomicAdd(&sg[4], f4); atomicAdd(&sg[5], f5);
                atomicAdd(&sg[6], f6); atomicAdd(&sg[7], f7);
                if (fl == 0) atomicAdd(&gcnt[b], 1.f);
                bacc = -1;
                cntacc = 0;
            }
        }
    }
    if (cntacc > 0) FLUSH();
#undef FLUSH
}

__global__ void final_kernel(const float* __restrict__ sums, const float* __restrict__ cnt,
                             const float* __restrict__ W, const float* __restrict__ b,
                             float* __restrict__ out) {
    int t = blockIdx.x * blockDim.x + threadIdx.x;
    if (t >= GG * NCLS) return;
    int g = t / NCLS, k = t % NCLS;
    float c = cnt[g];
    if (c < 1.f) c = 1.f;
    float inv = 1.f / c;
    float acc = b[k];
#pragma unroll
    for (int cc = 0; cc < 64; ++cc)
        acc = fmaf(sums[g * 64 + cc] * inv, W[cc * NCLS + k], acc);
    out[t] = acc;
}

// ---------------- launch ----------------

extern "C" void kernel_launch(void* const* d_in, const int* in_sizes, int n_in,
                              void* d_out, int out_size, void* d_ws, size_t ws_size,
                              hipStream_t stream) {
    const float* x    = (const float*)d_in[0];
    const int*   ei   = (const int*)d_in[1];   // [2,E]: src = ei, dst = ei+EE
    const int*   batch = (const int*)d_in[2];
    const float* W1 = (const float*)d_in[3];
    const float* a1s = (const float*)d_in[4];
    const float* a1d = (const float*)d_in[5];
    const float* b1 = (const float*)d_in[6];
    const float* W2 = (const float*)d_in[7];
    const float* a2s = (const float*)d_in[8];
    const float* a2d = (const float*)d_in[9];
    const float* b2 = (const float*)d_in[10];
    const float* W3 = (const float*)d_in[11];
    const float* a3s = (const float*)d_in[12];
    const float* a3d = (const float*)d_in[13];
    const float* b3 = (const float*)d_in[14];
    const float* linW = (const float*)d_in[15];
    const float* linb = (const float*)d_in[16];
    float* out = (float*)d_out;

    char* ws = (char*)d_ws;
    size_t off = 0;
    auto alloc = [&](size_t bytes) -> void* {
        void* p = ws + off;
        off = (off + bytes + 255) & ~(size_t)255;
        return p;
    };
    // contiguous zero-region: bfill | sums | gcnt  (one memset per replay)
    const size_t ZBYTES = (size_t)NB * 4 + (size_t)GG * 64 * 4 + (size_t)GG * 4;
    char* zr = (char*)alloc(ZBYTES);
    int*   bfill = (int*)zr;
    float* sums  = (float*)(zr + (size_t)NB * 4);
    float* gcnt  = sums + GG * 64;

    unsigned short* hA = (unsigned short*)alloc((size_t)NN * 64 * 2);  // bf16 feats (ping)
    unsigned short* hB = (unsigned short*)alloc((size_t)NN * 64 * 2);  // bf16 feats (pong)
    float* ALsA = (float*)alloc((size_t)NN * 8 * 4);
    float* ALdA = (float*)alloc((size_t)NN * 8 * 4);
    float* ALsB = (float*)alloc((size_t)NN * 8 * 4);
    float* ALdB = (float*)alloc((size_t)NN * 8 * 4);
    int2*  rpe  = (int2*)alloc((size_t)NN * 8);
    uint32* bpack = (uint32*)alloc((size_t)NB * BCAP * 4);
    int*   col  = (int*)alloc((size_t)NB * BCAP * 4);

    hipMemsetAsync(zr, 0, ZBYTES, stream);

    // bscatter || gemm1, roles interleaved by blockIdx%5 (1:4)
    pre_kernel<<<SBLK + GB, 512, 0, stream>>>(ei, ei + EE, bfill, bpack, EE,
                                              x, W1, a1s, a1d, hA, ALsA, ALdA);
    // CSR finalize
    bsort_kernel<<<NB, 1024, 0, stream>>>(bpack, bfill, rpe, col);

    const int AB = (NN + 15) / 16;    // 6250 blocks, 16 nodes each

    // layer1 agg + layer2 projection (fused, block-local, R9-proven)
    aggemm_kernel<<<AB, 256, 0, stream>>>(hA, ALsA, ALdA, rpe, col, b1,
                                          W2, a2s, a2d, hB, ALsB, ALdB, NN);
    // layer2 agg + layer3 projection
    aggemm_kernel<<<AB, 256, 0, stream>>>(hB, ALsB, ALdB, rpe, col, b2,
                                          W3, a3s, a3d, hA, ALsA, ALdA, NN);
    // layer3 agg (standalone, bf16 out) + split pool + final
    agg_kernel<<<AB, 256, 0, stream>>>(hA, ALsA, ALdA, rpe, col, b3, hB, NN);

    const int PB = ((NN + 31) / 32 + 3) / 4;   // 782 blocks
    pool_kernel<<<PB, 256, 0, stream>>>(hB, batch, sums, gcnt, NN);
    final_kernel<<<3, 256, 0, stream>>>(sums, gcnt, linW, linb, out);
}